// Round 6
// baseline (267.018 us; speedup 1.0000x reference)
//
#include <hip/hip_runtime.h>

#define DF 128      // feature dim
#define CAP 256     // staging capacity per (bucket, xcd-group) cell
#define OVFCAP 65536

typedef __bf16 bf16x8 __attribute__((ext_vector_type(8)));
typedef float f32x4 __attribute__((ext_vector_type(4)));

// ---------------------------------------------------------------- utilities
static __device__ __forceinline__ float lrelu(float x) {
  return x > 0.f ? x : 0.1f * x;
}
static __device__ __forceinline__ unsigned short f2bf(float f) {
  unsigned int u = __float_as_uint(f);
  u += 0x7FFFu + ((u >> 16) & 1u);
  return (unsigned short)(u >> 16);
}
static __device__ __forceinline__ float bf2f(unsigned short h) {
  return __uint_as_float((unsigned int)h << 16);
}

// ---------------------------------------------------------------- prep:
// blocks 0,1: split W1/W2 into bf16 hi/lo in MFMA B-fragment-linear order.
// block 2: detect int64 vs int32 edge_index.
__global__ void prep_kernel(const float* __restrict__ W1,
                            const float* __restrict__ W2,
                            unsigned short* __restrict__ wfrag,
                            const unsigned int* __restrict__ ei_u, int E,
                            int* __restrict__ flag) {
  if (blockIdx.x == 2) {
    __shared__ int any32;
    if (threadIdx.x == 0) any32 = 0;
    __syncthreads();
    long long idx = (long long)threadIdx.x * (E / 256);
    if (idx < E) {
      if (ei_u[2 * idx + 1] != 0u) any32 = 1;
    }
    __syncthreads();
    if (threadIdx.x == 0) flag[0] = any32 ? 0 : 1;  // 1 => int64
    return;
  }
  const float* W = (blockIdx.x == 0) ? W1 : W2;
  unsigned short* hi = wfrag + (size_t)blockIdx.x * 32768;
  unsigned short* lo = hi + 16384;
  for (int i = threadIdx.x; i < 16384; i += 256) {
    int k = i >> 7, c = i & 127;
    float w = W[i];
    unsigned short h = f2bf(w);
    unsigned short l = f2bf(w - bf2f(h));
    int fid = (((k >> 5) * 8) + (c >> 4)) * 64 + ((k >> 3) & 3) * 16 + (c & 15);
    int pos = fid * 8 + (k & 7);
    hi[pos] = h;
    lo[pos] = l;
  }
}

// ---------------------------------------------------------------- phase A:
// read edges, histogram targets, bin (src, c&63) into per-(bucket, xcd-group)
// staging cells. group = blockIdx&7 ~ XCD -> each staging line written by one
// XCD, cursor-sequential => full-line writes, no write-allocate blowup.
// NOTE: assumes n <= 65536 (src packed in 16 bits for overflow path,
// src<<6 in 22 bits for staging path).
__global__ __launch_bounds__(256) void binA_kernel(
    const void* __restrict__ ei, int E, const int* __restrict__ flag,
    int* __restrict__ cnt, int* __restrict__ cellcur,
    unsigned int* __restrict__ staging, unsigned int* __restrict__ ovf,
    int* __restrict__ ovfn) {
  int is64 = flag[0];
  int g = blockIdx.x & 7;
  for (int e = blockIdx.x * blockDim.x + threadIdx.x; e < E;
       e += gridDim.x * blockDim.x) {
    int src, c;
    if (is64) {
      const long long* p = (const long long*)ei;
      src = (int)p[e];
      c = (int)p[(size_t)E + e];
    } else {
      const int* p = (const int*)ei;
      src = p[e];
      c = p[(size_t)E + e];
    }
    atomicAdd(&cnt[c], 1);
    int cell = ((c >> 6) << 3) + g;
    int idx = atomicAdd(&cellcur[cell], 1);
    if (idx < CAP) {
      staging[(size_t)cell * CAP + idx] =
          ((unsigned int)src << 6) | (unsigned int)(c & 63);
    } else {
      int o = atomicAdd(ovfn, 1);
      if (o < OVFCAP) ovf[o] = ((unsigned int)src << 16) | (unsigned int)c;
    }
  }
}

// ---------------------------------------------------------------- scan (2 kernels), dis fused
__global__ void scan1_kernel(const int* __restrict__ cnt, int* __restrict__ off,
                             int* __restrict__ bsums, float* __restrict__ dis,
                             int n) {
  __shared__ int s[256];
  int t = threadIdx.x;
  int i = blockIdx.x * 256 + t;
  int v = (i < n) ? cnt[i] : 0;
  if (i < n) dis[i] = rsqrtf((float)(v + 1));  // deg incl self loop >= 1
  s[t] = v;
  __syncthreads();
  for (int d = 1; d < 256; d <<= 1) {
    int add = (t >= d) ? s[t - d] : 0;
    __syncthreads();
    s[t] += add;
    __syncthreads();
  }
  if (i < n) off[i] = s[t] - v;  // exclusive within chunk
  if (t == 255) bsums[blockIdx.x] = s[255];
}

__global__ void scan2_kernel(int* __restrict__ bsums, int G) {
  __shared__ int s[256];
  int t = threadIdx.x;
  int carry = 0;
  for (int base = 0; base < G; base += 256) {
    int i = base + t;
    int v = (i < G) ? bsums[i] : 0;
    s[t] = v;
    __syncthreads();
    for (int d = 1; d < 256; d <<= 1) {
      int add = (t >= d) ? s[t - d] : 0;
      __syncthreads();
      s[t] += add;
      __syncthreads();
    }
    if (i < G) bsums[i] = carry + s[t] - v;
    int tot = s[255];
    __syncthreads();
    carry += tot;
  }
}

// ---------------------------------------------------------------- phase B:
// one block per bucket; place staged entries into srcs via cursor atomics.
// Each bucket's srcs window (~4KB) is written by exactly one block.
__global__ __launch_bounds__(256) void binB_kernel(
    const unsigned int* __restrict__ staging, const int* __restrict__ cellcur,
    const int* __restrict__ off, const int* __restrict__ bsums,
    int* __restrict__ cursor, int* __restrict__ srcs,
    const unsigned int* __restrict__ ovf, const int* __restrict__ ovfn) {
  if (blockIdx.x == 0) {
    int m = ovfn[0];
    m = m < OVFCAP ? m : OVFCAP;
    for (int i = threadIdx.x; i < m; i += 256) {
      unsigned int v = ovf[i];
      int c = (int)(v & 0xFFFFu);
      int src = (int)(v >> 16);
      int pos = off[c] + bsums[c >> 8] + atomicAdd(&cursor[c], 1);
      srcs[pos] = src;
    }
  }
  int b = blockIdx.x;
  int c0 = b << 6;
#pragma unroll 1
  for (int g = 0; g < 8; ++g) {
    int cell = (b << 3) + g;
    int len = cellcur[cell];
    len = len < CAP ? len : CAP;
    const unsigned int* seg = staging + (size_t)cell * CAP;
    for (int i = threadIdx.x; i < len; i += 256) {
      unsigned int v = seg[i];
      int c = c0 + (int)(v & 63u);
      int src = (int)(v >> 6);
      int pos = off[c] + bsums[c >> 8] + atomicAdd(&cursor[c], 1);
      srcs[pos] = src;
    }
  }
}

// ---------------------------------------------------------------- MFMA GEMM, fp32 A (split hi/lo, 3 MFMA)
// G_bf16[n x 128] = dis[row] * (A_f32[n x 128] @ W[128 x 128])
__global__ __launch_bounds__(256, 8) void gemm_f32_kernel(
    const float* __restrict__ A, const unsigned short* __restrict__ wfrag,
    const float* __restrict__ dis, unsigned short* __restrict__ G, int n) {
  __shared__ unsigned short Ah[2][4][64][8];
  __shared__ unsigned short Al[2][4][64][8];
  __shared__ float disS[32];
  int tid = threadIdx.x;
  int row0 = blockIdx.x * 32;

  if (tid < 32) {
    int gr = row0 + tid;
    disS[tid] = (gr < n) ? dis[gr] : 0.f;
  }

  const float4* A4 = (const float4*)A;
#pragma unroll
  for (int it = 0; it < 4; ++it) {
    int fi = it * 256 + tid;
    int row = fi >> 5;          // 0..31
    int c4 = fi & 31;           // float4 index along k
    int gr = row0 + row;
    float4 v = make_float4(0.f, 0.f, 0.f, 0.f);
    if (gr < n) v = A4[(size_t)gr * 32 + c4];
    unsigned short h0 = f2bf(v.x), h1 = f2bf(v.y), h2 = f2bf(v.z), h3 = f2bf(v.w);
    unsigned short l0 = f2bf(v.x - bf2f(h0)), l1 = f2bf(v.y - bf2f(h1));
    unsigned short l2 = f2bf(v.z - bf2f(h2)), l3 = f2bf(v.w - bf2f(h3));
    int band = row >> 4;
    int kslab = c4 >> 3;
    int lane = ((c4 >> 1) & 3) * 16 + (row & 15);
    int e0 = (c4 & 1) * 4;
    *(uint2*)&Ah[band][kslab][lane][e0] =
        make_uint2((unsigned int)h0 | ((unsigned int)h1 << 16),
                   (unsigned int)h2 | ((unsigned int)h3 << 16));
    *(uint2*)&Al[band][kslab][lane][e0] =
        make_uint2((unsigned int)l0 | ((unsigned int)l1 << 16),
                   (unsigned int)l2 | ((unsigned int)l3 << 16));
  }
  __syncthreads();

  int w = tid >> 6, lane = tid & 63;
  int band = w & 1, ch = w >> 1;

  f32x4 acc[4];
#pragma unroll
  for (int t = 0; t < 4; ++t) acc[t] = (f32x4){0.f, 0.f, 0.f, 0.f};

#pragma unroll
  for (int ks = 0; ks < 4; ++ks) {
    bf16x8 ahi = *(const bf16x8*)&Ah[band][ks][lane][0];
    bf16x8 alo = *(const bf16x8*)&Al[band][ks][lane][0];
#pragma unroll
    for (int ct = 0; ct < 4; ++ct) {
      size_t fb = ((size_t)(ks * 8 + ch * 4 + ct) * 64 + lane) * 8;
      bf16x8 whi = *(const bf16x8*)&wfrag[fb];
      bf16x8 wlo = *(const bf16x8*)&wfrag[16384 + fb];
      acc[ct] = __builtin_amdgcn_mfma_f32_16x16x32_bf16(ahi, whi, acc[ct], 0, 0, 0);
      acc[ct] = __builtin_amdgcn_mfma_f32_16x16x32_bf16(ahi, wlo, acc[ct], 0, 0, 0);
      acc[ct] = __builtin_amdgcn_mfma_f32_16x16x32_bf16(alo, whi, acc[ct], 0, 0, 0);
    }
  }

#pragma unroll
  for (int ct = 0; ct < 4; ++ct) {
    int col = ch * 64 + ct * 16 + (lane & 15);
#pragma unroll
    for (int r = 0; r < 4; ++r) {
      int lrow = band * 16 + ((lane >> 4) << 2) + r;
      int grow = row0 + lrow;
      if (grow < n) G[(size_t)grow * DF + col] = f2bf(acc[ct][r] * disS[lrow]);
    }
  }
}

// ---------------------------------------------------------------- MFMA GEMM, bf16 A (2 MFMA)
__global__ __launch_bounds__(256, 8) void gemm_bf16_kernel(
    const unsigned short* __restrict__ A, const unsigned short* __restrict__ wfrag,
    const float* __restrict__ dis, unsigned short* __restrict__ G, int n) {
  __shared__ unsigned short Ah[2][4][64][8];
  __shared__ float disS[32];
  int tid = threadIdx.x;
  int row0 = blockIdx.x * 32;

  if (tid < 32) {
    int gr = row0 + tid;
    disS[tid] = (gr < n) ? dis[gr] : 0.f;
  }

  const uint4* A4 = (const uint4*)A;  // 8 bf16 per uint4
#pragma unroll
  for (int it = 0; it < 2; ++it) {
    int fi = it * 256 + tid;    // 0..511
    int row = fi >> 4;          // 0..31
    int m = fi & 15;            // 8-k group
    int gr = row0 + row;
    uint4 v = make_uint4(0u, 0u, 0u, 0u);
    if (gr < n) v = A4[(size_t)gr * 16 + m];
    int band = row >> 4;
    int kslab = m >> 2;
    int lane = (m & 3) * 16 + (row & 15);
    *(uint4*)&Ah[band][kslab][lane][0] = v;
  }
  __syncthreads();

  int w = tid >> 6, lane = tid & 63;
  int band = w & 1, ch = w >> 1;

  f32x4 acc[4];
#pragma unroll
  for (int t = 0; t < 4; ++t) acc[t] = (f32x4){0.f, 0.f, 0.f, 0.f};

#pragma unroll
  for (int ks = 0; ks < 4; ++ks) {
    bf16x8 ahi = *(const bf16x8*)&Ah[band][ks][lane][0];
#pragma unroll
    for (int ct = 0; ct < 4; ++ct) {
      size_t fb = ((size_t)(ks * 8 + ch * 4 + ct) * 64 + lane) * 8;
      bf16x8 whi = *(const bf16x8*)&wfrag[fb];
      bf16x8 wlo = *(const bf16x8*)&wfrag[16384 + fb];
      acc[ct] = __builtin_amdgcn_mfma_f32_16x16x32_bf16(ahi, whi, acc[ct], 0, 0, 0);
      acc[ct] = __builtin_amdgcn_mfma_f32_16x16x32_bf16(ahi, wlo, acc[ct], 0, 0, 0);
    }
  }

#pragma unroll
  for (int ct = 0; ct < 4; ++ct) {
    int col = ch * 64 + ct * 16 + (lane & 15);
#pragma unroll
    for (int r = 0; r < 4; ++r) {
      int lrow = band * 16 + ((lane >> 4) << 2) + r;
      int grow = row0 + lrow;
      if (grow < n) G[(size_t)grow * DF + col] = f2bf(acc[ct][r] * disS[lrow]);
    }
  }
}

// ---------------------------------------------------------------- aggregation: one wave per node
// acc = sum_{s in N(t)} g[s] + g[t];  OUT==0: write bf16(dis*acc + b)
//                                     OUT==1: write f32 lrelu(dis*acc + b)
template <int OUT>
__global__ __launch_bounds__(1024) void agg_kernel(
    const unsigned short* __restrict__ g, const int* __restrict__ srcs,
    const int* __restrict__ off, const int* __restrict__ bsums,
    const int* __restrict__ cnt, const float* __restrict__ dis,
    const float* __restrict__ bias, void* __restrict__ outv, int n) {
  int wid = (blockIdx.x * blockDim.x + threadIdx.x) >> 6;
  int lane = threadIdx.x & 63;
  if (wid >= n) return;

  float diw = dis[wid];
  unsigned int us = ((const unsigned int*)(g + (size_t)wid * DF))[lane];
  float ax = __uint_as_float(us << 16);         // self term g[wid]
  float ay = __uint_as_float(us & 0xFFFF0000u);

  int s = off[wid] + bsums[wid >> 8];
  int e = s + cnt[wid];
  // predicated unroll-16: clamp index to e-1, zero invalid contributions
  for (int j = s; j < e; j += 16) {
    int src[16];
    unsigned int u[16];
#pragma unroll
    for (int q = 0; q < 16; ++q) {
      int idx = j + q;
      src[q] = srcs[idx < e ? idx : e - 1];
    }
#pragma unroll
    for (int q = 0; q < 16; ++q)
      u[q] = ((const unsigned int*)(g + (size_t)src[q] * DF))[lane];
#pragma unroll
    for (int q = 0; q < 16; ++q) {
      bool v = (j + q) < e;
      float vx = __uint_as_float(u[q] << 16);
      float vy = __uint_as_float(u[q] & 0xFFFF0000u);
      ax += v ? vx : 0.f;
      ay += v ? vy : 0.f;
    }
  }

  float2 bb = ((const float2*)bias)[lane];
  ax = fmaf(ax, diw, bb.x);
  ay = fmaf(ay, diw, bb.y);
  if (OUT == 0) {
    unsigned int pack =
        (unsigned int)f2bf(ax) | ((unsigned int)f2bf(ay) << 16);
    ((unsigned int*)((unsigned short*)outv + (size_t)wid * DF))[lane] = pack;
  } else {
    float2 r;
    r.x = lrelu(ax);
    r.y = lrelu(ay);
    ((float2*)((float*)outv + (size_t)wid * DF))[lane] = r;
  }
}

// ---------------------------------------------------------------- launch
extern "C" void kernel_launch(void* const* d_in, const int* in_sizes, int n_in,
                              void* d_out, int out_size, void* d_ws, size_t ws_size,
                              hipStream_t stream) {
  const float* x  = (const float*)d_in[0];
  const void*  ei = d_in[1];
  const float* W1 = (const float*)d_in[2];
  const float* b1 = (const float*)d_in[3];
  const float* W2 = (const float*)d_in[4];
  const float* b2 = (const float*)d_in[5];
  float* out = (float*)d_out;

  int n = in_sizes[0] / DF;  // 50000
  int E = in_sizes[1] / 2;   // 800000
  int NBUCK = (n + 63) >> 6; // 782

  // workspace carve (16B aligned)
  char* w = (char*)d_ws;
  auto carve = [&](size_t bytes) {
    char* p = w;
    w += (bytes + 15) & ~(size_t)15;
    return p;
  };
  float* dis    = (float*)carve((size_t)n * 4);
  // ---- contiguous zero block: cnt, cursor, cellcur, ovfn (single memset)
  int*   cnt     = (int*)carve((size_t)n * 4);
  int*   cursor  = (int*)carve((size_t)n * 4);
  int*   cellcur = (int*)carve((size_t)NBUCK * 8 * 4);
  int*   ovfn    = (int*)carve(16);
  size_t zbytes  = (char*)w - (char*)cnt;
  // ----
  int*   off    = (int*)carve((size_t)n * 4);
  int*   bsums  = (int*)carve(4096);
  int*   flag   = (int*)carve(16);
  unsigned short* wfrag = (unsigned short*)carve(65536 * 2);  // 2 x (hi+lo)
  unsigned int* staging = (unsigned int*)carve((size_t)NBUCK * 8 * CAP * 4);
  unsigned int* ovf     = (unsigned int*)carve((size_t)OVFCAP * 4);
  int*   srcs   = (int*)carve((size_t)E * 4);
  unsigned short* bufG = (unsigned short*)carve((size_t)n * DF * 2);
  unsigned short* bufH = (unsigned short*)carve((size_t)n * DF * 2);

  int gE = (E + 255) / 256;    // 3125
  int gN = (n + 255) / 256;    // 196
  int G  = gN;                 // scan blocks

  hipMemsetAsync(cnt, 0, zbytes, stream);  // cnt + cursor + cellcur + ovfn

  prep_kernel<<<3, 256, 0, stream>>>(W1, W2, wfrag, (const unsigned int*)ei, E, flag);
  binA_kernel<<<gE, 256, 0, stream>>>(ei, E, flag, cnt, cellcur, staging, ovf, ovfn);
  scan1_kernel<<<G, 256, 0, stream>>>(cnt, off, bsums, dis, n);
  scan2_kernel<<<1, 256, 0, stream>>>(bsums, G);
  binB_kernel<<<NBUCK, 256, 0, stream>>>(staging, cellcur, off, bsums, cursor,
                                         srcs, ovf, ovfn);

  int gGemm = (n + 31) / 32;        // 1563
  int gAgg  = (n + 15) / 16;        // 3125 (16 waves/block)

  // layer 1: g1 = dis * bf16(x @ W1) ; h1 = bf16(dis*(sum g1 + g1_self) + b1)
  gemm_f32_kernel<<<gGemm, 256, 0, stream>>>(x, wfrag, dis, bufG, n);
  agg_kernel<0><<<gAgg, 1024, 0, stream>>>(bufG, srcs, off, bsums, cnt, dis, b1,
                                           bufH, n);

  // layer 2: g2 = dis * bf16(h1 @ W2) ; out = lrelu(dis*(sum g2 + g2_self) + b2)
  gemm_bf16_kernel<<<gGemm, 256, 0, stream>>>(bufH, wfrag + 32768, dis, bufG, n);
  agg_kernel<1><<<gAgg, 1024, 0, stream>>>(bufG, srcs, off, bsums, cnt, dis, b2,
                                           out, n);
}

// Round 7
// 245.831 us; speedup vs baseline: 1.0862x; 1.0862x over previous
//
#include <hip/hip_runtime.h>

#define DF 128      // feature dim
#define CHUNK 4096  // edges per chunk in counting sort
#define LSTCAP 6144 // LDS staging cap in p2 (bucket avg ~4096, 32 sigma slack)

typedef __bf16 bf16x8 __attribute__((ext_vector_type(8)));
typedef float f32x4 __attribute__((ext_vector_type(4)));

// NOTE: packing assumes n <= 65536 (problem fixes n = 50000).

// ---------------------------------------------------------------- utilities
static __device__ __forceinline__ float lrelu(float x) {
  return x > 0.f ? x : 0.1f * x;
}
static __device__ __forceinline__ unsigned short f2bf(float f) {
  unsigned int u = __float_as_uint(f);
  u += 0x7FFFu + ((u >> 16) & 1u);
  return (unsigned short)(u >> 16);
}
static __device__ __forceinline__ float bf2f(unsigned short h) {
  return __uint_as_float((unsigned int)h << 16);
}

// ---------------------------------------------------------------- prep:
// blocks 0,1: split W1/W2 into bf16 hi/lo in MFMA B-fragment-linear order.
// block 2: detect int64 vs int32 edge_index.
__global__ void prep_kernel(const float* __restrict__ W1,
                            const float* __restrict__ W2,
                            unsigned short* __restrict__ wfrag,
                            const unsigned int* __restrict__ ei_u, int E,
                            int* __restrict__ flag) {
  if (blockIdx.x == 2) {
    __shared__ int any32;
    if (threadIdx.x == 0) any32 = 0;
    __syncthreads();
    long long idx = (long long)threadIdx.x * (E / 256);
    if (idx < E) {
      if (ei_u[2 * idx + 1] != 0u) any32 = 1;
    }
    __syncthreads();
    if (threadIdx.x == 0) flag[0] = any32 ? 0 : 1;  // 1 => int64
    return;
  }
  const float* W = (blockIdx.x == 0) ? W1 : W2;
  unsigned short* hi = wfrag + (size_t)blockIdx.x * 32768;
  unsigned short* lo = hi + 16384;
  for (int i = threadIdx.x; i < 16384; i += 256) {
    int k = i >> 7, c = i & 127;
    float w = W[i];
    unsigned short h = f2bf(w);
    unsigned short l = f2bf(w - bf2f(h));
    int fid = (((k >> 5) * 8) + (c >> 4)) * 64 + ((k >> 3) & 3) * 16 + (c & 15);
    int pos = fid * 8 + (k & 7);
    hi[pos] = h;
    lo[pos] = l;
  }
}

// ---------------------------------------------------------------- pass 1a:
// per-chunk bucket histogram (bucket = target >> 8), LDS only, no global atomics.
__global__ __launch_bounds__(256) void p1a_kernel(const void* __restrict__ ei,
                                                  int E,
                                                  const int* __restrict__ flag,
                                                  int* __restrict__ M,
                                                  int NBUCK) {
  __shared__ int h[256];
  int tid = threadIdx.x;
  h[tid] = 0;
  __syncthreads();
  int is64 = flag[0];
  int base = blockIdx.x * CHUNK;
  int end = min(base + CHUNK, E);
  if (is64) {
    const long long* p = (const long long*)ei;
    for (int i = base + tid; i < end; i += 256)
      atomicAdd(&h[((int)p[(size_t)E + i]) >> 8], 1);
  } else {
    const int* p = (const int*)ei;
    for (int i = base + tid; i < end; i += 256)
      atomicAdd(&h[p[(size_t)E + i] >> 8], 1);
  }
  __syncthreads();
  if (tid < NBUCK) M[blockIdx.x * NBUCK + tid] = h[tid];
}

// ---------------------------------------------------------------- matrix scan:
// column-wise exclusive scan of M[chunk][bucket] + bucket base offsets.
// After this, M[ch][b] = exact staging start for (chunk ch, bucket b).
__global__ __launch_bounds__(256) void matscan_kernel(int* __restrict__ M,
                                                      int* __restrict__ bstart,
                                                      int NBUCK, int NCHUNK,
                                                      int E) {
  __shared__ int s[256];
  int tid = threadIdx.x;
  int total = 0;
  if (tid < NBUCK) {
    for (int ch = 0; ch < NCHUNK; ++ch) {
      int t = M[ch * NBUCK + tid];
      M[ch * NBUCK + tid] = total;
      total += t;
    }
  }
  s[tid] = total;
  __syncthreads();
  for (int d = 1; d < 256; d <<= 1) {
    int add = (tid >= d) ? s[tid - d] : 0;
    __syncthreads();
    s[tid] += add;
    __syncthreads();
  }
  int excl = s[tid] - total;
  if (tid < NBUCK) {
    bstart[tid] = excl;
    for (int ch = 0; ch < NCHUNK; ++ch) M[ch * NBUCK + tid] += excl;
  }
  if (tid == 0) bstart[NBUCK] = E;
}

// ---------------------------------------------------------------- pass 1c:
// scatter packed (src<<16|c) into exact per-(chunk,bucket) staging slots.
// Ranks via LDS atomics; every block writes a disjoint dense-ish region.
__global__ __launch_bounds__(256) void p1c_kernel(
    const void* __restrict__ ei, int E, const int* __restrict__ flag,
    const int* __restrict__ M, int NBUCK, unsigned int* __restrict__ staging) {
  __shared__ int rowM[256];
  __shared__ int lcur[256];
  int tid = threadIdx.x;
  if (tid < NBUCK) rowM[tid] = M[blockIdx.x * NBUCK + tid];
  lcur[tid] = 0;
  __syncthreads();
  int is64 = flag[0];
  int base = blockIdx.x * CHUNK;
  int end = min(base + CHUNK, E);
  for (int i = base + tid; i < end; i += 256) {
    int src, c;
    if (is64) {
      const long long* p = (const long long*)ei;
      src = (int)p[i];
      c = (int)p[(size_t)E + i];
    } else {
      const int* p = (const int*)ei;
      src = p[i];
      c = p[(size_t)E + i];
    }
    int b = c >> 8;
    int r = atomicAdd(&lcur[b], 1);
    staging[rowM[b] + r] = ((unsigned int)src << 16) | (unsigned int)c;
  }
}

// ---------------------------------------------------------------- pass 2:
// one block per bucket: LDS histogram + scan of the 256 nodes, emit
// off/cnt/dis densely, scatter srcs (ushort) into the bucket's CSR window.
__global__ __launch_bounds__(256) void p2_kernel(
    const unsigned int* __restrict__ staging, const int* __restrict__ bstart,
    int* __restrict__ off, int* __restrict__ cnt, float* __restrict__ dis,
    unsigned short* __restrict__ srcs, int n) {
  __shared__ int h[256], ex[256], lcur[256];
  __shared__ unsigned int lst[LSTCAP];
  int tid = threadIdx.x;
  int b = blockIdx.x;
  int base = bstart[b];
  int len = bstart[b + 1] - base;
  h[tid] = 0;
  lcur[tid] = 0;
  __syncthreads();
  for (int i = tid; i < len; i += 256) {
    unsigned int v = staging[base + i];
    if (i < LSTCAP) lst[i] = v;
    atomicAdd(&h[v & 255u], 1);
  }
  __syncthreads();
  int my = h[tid];
  ex[tid] = my;
  __syncthreads();
  for (int d = 1; d < 256; d <<= 1) {
    int add = (tid >= d) ? ex[tid - d] : 0;
    __syncthreads();
    ex[tid] += add;
    __syncthreads();
  }
  int excl = ex[tid] - my;  // exclusive within bucket
  ex[tid] = excl;
  int node = (b << 8) + tid;
  if (node < n) {
    off[node] = base + excl;
    cnt[node] = my;
    dis[node] = rsqrtf((float)(my + 1));  // deg incl self loop >= 1
  }
  __syncthreads();
  for (int i = tid; i < len; i += 256) {
    unsigned int v = (i < LSTCAP) ? lst[i] : staging[base + i];
    int ci = (int)(v & 255u);
    int r = atomicAdd(&lcur[ci], 1);
    srcs[base + ex[ci] + r] = (unsigned short)(v >> 16);
  }
}

// ---------------------------------------------------------------- MFMA GEMM, fp32 A (split hi/lo, 3 MFMA)
// G_bf16[n x 128] = dis[row] * (A_f32[n x 128] @ W[128 x 128])
__global__ __launch_bounds__(256, 8) void gemm_f32_kernel(
    const float* __restrict__ A, const unsigned short* __restrict__ wfrag,
    const float* __restrict__ dis, unsigned short* __restrict__ G, int n) {
  __shared__ unsigned short Ah[2][4][64][8];
  __shared__ unsigned short Al[2][4][64][8];
  __shared__ float disS[32];
  int tid = threadIdx.x;
  int row0 = blockIdx.x * 32;

  if (tid < 32) {
    int gr = row0 + tid;
    disS[tid] = (gr < n) ? dis[gr] : 0.f;
  }

  const float4* A4 = (const float4*)A;
#pragma unroll
  for (int it = 0; it < 4; ++it) {
    int fi = it * 256 + tid;
    int row = fi >> 5;          // 0..31
    int c4 = fi & 31;           // float4 index along k
    int gr = row0 + row;
    float4 v = make_float4(0.f, 0.f, 0.f, 0.f);
    if (gr < n) v = A4[(size_t)gr * 32 + c4];
    unsigned short h0 = f2bf(v.x), h1 = f2bf(v.y), h2 = f2bf(v.z), h3 = f2bf(v.w);
    unsigned short l0 = f2bf(v.x - bf2f(h0)), l1 = f2bf(v.y - bf2f(h1));
    unsigned short l2 = f2bf(v.z - bf2f(h2)), l3 = f2bf(v.w - bf2f(h3));
    int band = row >> 4;
    int kslab = c4 >> 3;
    int lane = ((c4 >> 1) & 3) * 16 + (row & 15);
    int e0 = (c4 & 1) * 4;
    *(uint2*)&Ah[band][kslab][lane][e0] =
        make_uint2((unsigned int)h0 | ((unsigned int)h1 << 16),
                   (unsigned int)h2 | ((unsigned int)h3 << 16));
    *(uint2*)&Al[band][kslab][lane][e0] =
        make_uint2((unsigned int)l0 | ((unsigned int)l1 << 16),
                   (unsigned int)l2 | ((unsigned int)l3 << 16));
  }
  __syncthreads();

  int w = tid >> 6, lane = tid & 63;
  int band = w & 1, ch = w >> 1;

  f32x4 acc[4];
#pragma unroll
  for (int t = 0; t < 4; ++t) acc[t] = (f32x4){0.f, 0.f, 0.f, 0.f};

#pragma unroll
  for (int ks = 0; ks < 4; ++ks) {
    bf16x8 ahi = *(const bf16x8*)&Ah[band][ks][lane][0];
    bf16x8 alo = *(const bf16x8*)&Al[band][ks][lane][0];
#pragma unroll
    for (int ct = 0; ct < 4; ++ct) {
      size_t fb = ((size_t)(ks * 8 + ch * 4 + ct) * 64 + lane) * 8;
      bf16x8 whi = *(const bf16x8*)&wfrag[fb];
      bf16x8 wlo = *(const bf16x8*)&wfrag[16384 + fb];
      acc[ct] = __builtin_amdgcn_mfma_f32_16x16x32_bf16(ahi, whi, acc[ct], 0, 0, 0);
      acc[ct] = __builtin_amdgcn_mfma_f32_16x16x32_bf16(ahi, wlo, acc[ct], 0, 0, 0);
      acc[ct] = __builtin_amdgcn_mfma_f32_16x16x32_bf16(alo, whi, acc[ct], 0, 0, 0);
    }
  }

#pragma unroll
  for (int ct = 0; ct < 4; ++ct) {
    int col = ch * 64 + ct * 16 + (lane & 15);
#pragma unroll
    for (int r = 0; r < 4; ++r) {
      int lrow = band * 16 + ((lane >> 4) << 2) + r;
      int grow = row0 + lrow;
      if (grow < n) G[(size_t)grow * DF + col] = f2bf(acc[ct][r] * disS[lrow]);
    }
  }
}

// ---------------------------------------------------------------- MFMA GEMM, bf16 A (2 MFMA)
__global__ __launch_bounds__(256, 8) void gemm_bf16_kernel(
    const unsigned short* __restrict__ A, const unsigned short* __restrict__ wfrag,
    const float* __restrict__ dis, unsigned short* __restrict__ G, int n) {
  __shared__ unsigned short Ah[2][4][64][8];
  __shared__ float disS[32];
  int tid = threadIdx.x;
  int row0 = blockIdx.x * 32;

  if (tid < 32) {
    int gr = row0 + tid;
    disS[tid] = (gr < n) ? dis[gr] : 0.f;
  }

  const uint4* A4 = (const uint4*)A;  // 8 bf16 per uint4
#pragma unroll
  for (int it = 0; it < 2; ++it) {
    int fi = it * 256 + tid;    // 0..511
    int row = fi >> 4;          // 0..31
    int m = fi & 15;            // 8-k group
    int gr = row0 + row;
    uint4 v = make_uint4(0u, 0u, 0u, 0u);
    if (gr < n) v = A4[(size_t)gr * 16 + m];
    int band = row >> 4;
    int kslab = m >> 2;
    int lane = (m & 3) * 16 + (row & 15);
    *(uint4*)&Ah[band][kslab][lane][0] = v;
  }
  __syncthreads();

  int w = tid >> 6, lane = tid & 63;
  int band = w & 1, ch = w >> 1;

  f32x4 acc[4];
#pragma unroll
  for (int t = 0; t < 4; ++t) acc[t] = (f32x4){0.f, 0.f, 0.f, 0.f};

#pragma unroll
  for (int ks = 0; ks < 4; ++ks) {
    bf16x8 ahi = *(const bf16x8*)&Ah[band][ks][lane][0];
#pragma unroll
    for (int ct = 0; ct < 4; ++ct) {
      size_t fb = ((size_t)(ks * 8 + ch * 4 + ct) * 64 + lane) * 8;
      bf16x8 whi = *(const bf16x8*)&wfrag[fb];
      bf16x8 wlo = *(const bf16x8*)&wfrag[16384 + fb];
      acc[ct] = __builtin_amdgcn_mfma_f32_16x16x32_bf16(ahi, whi, acc[ct], 0, 0, 0);
      acc[ct] = __builtin_amdgcn_mfma_f32_16x16x32_bf16(ahi, wlo, acc[ct], 0, 0, 0);
    }
  }

#pragma unroll
  for (int ct = 0; ct < 4; ++ct) {
    int col = ch * 64 + ct * 16 + (lane & 15);
#pragma unroll
    for (int r = 0; r < 4; ++r) {
      int lrow = band * 16 + ((lane >> 4) << 2) + r;
      int grow = row0 + lrow;
      if (grow < n) G[(size_t)grow * DF + col] = f2bf(acc[ct][r] * disS[lrow]);
    }
  }
}

// ---------------------------------------------------------------- aggregation: one wave per node
// acc = sum_{s in N(t)} g[s] + g[t];  OUT==0: write bf16(dis*acc + b)
//                                     OUT==1: write f32 lrelu(dis*acc + b)
template <int OUT>
__global__ __launch_bounds__(1024) void agg_kernel(
    const unsigned short* __restrict__ g, const unsigned short* __restrict__ srcs,
    const int* __restrict__ off, const int* __restrict__ cnt,
    const float* __restrict__ dis, const float* __restrict__ bias,
    void* __restrict__ outv, int n) {
  int wid = (blockIdx.x * blockDim.x + threadIdx.x) >> 6;
  int lane = threadIdx.x & 63;
  if (wid >= n) return;

  float diw = dis[wid];
  unsigned int us = ((const unsigned int*)(g + (size_t)wid * DF))[lane];
  float ax = __uint_as_float(us << 16);         // self term g[wid]
  float ay = __uint_as_float(us & 0xFFFF0000u);

  int s = off[wid];
  int e = s + cnt[wid];
  // predicated unroll-16: clamp index to e-1, zero invalid contributions
  for (int j = s; j < e; j += 16) {
    int src[16];
    unsigned int u[16];
#pragma unroll
    for (int q = 0; q < 16; ++q) {
      int idx = j + q;
      src[q] = (int)srcs[idx < e ? idx : e - 1];
    }
#pragma unroll
    for (int q = 0; q < 16; ++q)
      u[q] = ((const unsigned int*)(g + (size_t)src[q] * DF))[lane];
#pragma unroll
    for (int q = 0; q < 16; ++q) {
      bool v = (j + q) < e;
      float vx = __uint_as_float(u[q] << 16);
      float vy = __uint_as_float(u[q] & 0xFFFF0000u);
      ax += v ? vx : 0.f;
      ay += v ? vy : 0.f;
    }
  }

  float2 bb = ((const float2*)bias)[lane];
  ax = fmaf(ax, diw, bb.x);
  ay = fmaf(ay, diw, bb.y);
  if (OUT == 0) {
    unsigned int pack =
        (unsigned int)f2bf(ax) | ((unsigned int)f2bf(ay) << 16);
    ((unsigned int*)((unsigned short*)outv + (size_t)wid * DF))[lane] = pack;
  } else {
    float2 r;
    r.x = lrelu(ax);
    r.y = lrelu(ay);
    ((float2*)((float*)outv + (size_t)wid * DF))[lane] = r;
  }
}

// ---------------------------------------------------------------- launch
extern "C" void kernel_launch(void* const* d_in, const int* in_sizes, int n_in,
                              void* d_out, int out_size, void* d_ws, size_t ws_size,
                              hipStream_t stream) {
  const float* x  = (const float*)d_in[0];
  const void*  ei = d_in[1];
  const float* W1 = (const float*)d_in[2];
  const float* b1 = (const float*)d_in[3];
  const float* W2 = (const float*)d_in[4];
  const float* b2 = (const float*)d_in[5];
  float* out = (float*)d_out;

  int n = in_sizes[0] / DF;  // 50000
  int E = in_sizes[1] / 2;   // 800000
  int NBUCK = (n + 255) >> 8;              // 196
  int NCHUNK = (E + CHUNK - 1) / CHUNK;    // 196

  // workspace carve (16B aligned)
  char* w = (char*)d_ws;
  auto carve = [&](size_t bytes) {
    char* p = w;
    w += (bytes + 15) & ~(size_t)15;
    return p;
  };
  float* dis    = (float*)carve((size_t)n * 4);
  int*   cnt    = (int*)carve((size_t)n * 4);
  int*   off    = (int*)carve((size_t)n * 4);
  int*   flag   = (int*)carve(16);
  int*   bstart = (int*)carve((size_t)(NBUCK + 1) * 4);
  int*   M      = (int*)carve((size_t)NCHUNK * NBUCK * 4);
  unsigned short* wfrag = (unsigned short*)carve(65536 * 2);  // 2 x (hi+lo)
  unsigned int* staging = (unsigned int*)carve((size_t)E * 4);
  unsigned short* srcs  = (unsigned short*)carve((size_t)E * 2);
  unsigned short* bufG  = (unsigned short*)carve((size_t)n * DF * 2);
  unsigned short* bufH  = (unsigned short*)carve((size_t)n * DF * 2);

  // CSR build: exact counting sort by bucket = target>>8 (no global atomics)
  prep_kernel<<<3, 256, 0, stream>>>(W1, W2, wfrag, (const unsigned int*)ei, E, flag);
  p1a_kernel<<<NCHUNK, 256, 0, stream>>>(ei, E, flag, M, NBUCK);
  matscan_kernel<<<1, 256, 0, stream>>>(M, bstart, NBUCK, NCHUNK, E);
  p1c_kernel<<<NCHUNK, 256, 0, stream>>>(ei, E, flag, M, NBUCK, staging);
  p2_kernel<<<NBUCK, 256, 0, stream>>>(staging, bstart, off, cnt, dis, srcs, n);

  int gGemm = (n + 31) / 32;        // 1563
  int gAgg  = (n + 15) / 16;        // 3125 (16 waves/block)

  // layer 1: g1 = dis * bf16(x @ W1) ; h1 = bf16(dis*(sum g1 + g1_self) + b1)
  gemm_f32_kernel<<<gGemm, 256, 0, stream>>>(x, wfrag, dis, bufG, n);
  agg_kernel<0><<<gAgg, 1024, 0, stream>>>(bufG, srcs, off, cnt, dis, b1, bufH, n);

  // layer 2: g2 = dis * bf16(h1 @ W2) ; out = lrelu(dis*(sum g2 + g2_self) + b2)
  gemm_bf16_kernel<<<gGemm, 256, 0, stream>>>(bufH, wfrag + 32768, dis, bufG, n);
  agg_kernel<1><<<gAgg, 1024, 0, stream>>>(bufG, srcs, off, cnt, dis, b2, out, n);
}

// Round 8
// 178.856 us; speedup vs baseline: 1.4929x; 1.3745x over previous
//
#include <hip/hip_runtime.h>

#define DF 128      // feature dim
#define CHUNK 4096  // edges per chunk in counting sort
#define LSTCAP 6144 // LDS staging cap in p2 (bucket avg ~4096, 32 sigma slack)

typedef __bf16 bf16x8 __attribute__((ext_vector_type(8)));
typedef float f32x4 __attribute__((ext_vector_type(4)));

// NOTE: packing assumes n <= 65536, NBUCK <= 256, NCHUNK <= 256
// (problem fixes n = 50000, E = 800000 -> NBUCK = 196, NCHUNK = 196).

// ---------------------------------------------------------------- utilities
static __device__ __forceinline__ float lrelu(float x) {
  return x > 0.f ? x : 0.1f * x;
}
static __device__ __forceinline__ unsigned short f2bf(float f) {
  unsigned int u = __float_as_uint(f);
  u += 0x7FFFu + ((u >> 16) & 1u);
  return (unsigned short)(u >> 16);
}
static __device__ __forceinline__ float bf2f(unsigned short h) {
  return __uint_as_float((unsigned int)h << 16);
}

// ---------------------------------------------------------------- prep:
// blocks 0,1: split W1/W2 into bf16 hi/lo in MFMA B-fragment-linear order.
// block 2: detect int64 vs int32 edge_index.
__global__ void prep_kernel(const float* __restrict__ W1,
                            const float* __restrict__ W2,
                            unsigned short* __restrict__ wfrag,
                            const unsigned int* __restrict__ ei_u, int E,
                            int* __restrict__ flag) {
  if (blockIdx.x == 2) {
    __shared__ int any32;
    if (threadIdx.x == 0) any32 = 0;
    __syncthreads();
    long long idx = (long long)threadIdx.x * (E / 256);
    if (idx < E) {
      if (ei_u[2 * idx + 1] != 0u) any32 = 1;
    }
    __syncthreads();
    if (threadIdx.x == 0) flag[0] = any32 ? 0 : 1;  // 1 => int64
    return;
  }
  const float* W = (blockIdx.x == 0) ? W1 : W2;
  unsigned short* hi = wfrag + (size_t)blockIdx.x * 32768;
  unsigned short* lo = hi + 16384;
  for (int i = threadIdx.x; i < 16384; i += 256) {
    int k = i >> 7, c = i & 127;
    float w = W[i];
    unsigned short h = f2bf(w);
    unsigned short l = f2bf(w - bf2f(h));
    int fid = (((k >> 5) * 8) + (c >> 4)) * 64 + ((k >> 3) & 3) * 16 + (c & 15);
    int pos = fid * 8 + (k & 7);
    hi[pos] = h;
    lo[pos] = l;
  }
}

// ---------------------------------------------------------------- pass 1a:
// per-chunk bucket histogram (bucket = target >> 8), LDS only.
// M stored TRANSPOSED: M[bucket * NCHUNK + chunk].
__global__ __launch_bounds__(256) void p1a_kernel(const void* __restrict__ ei,
                                                  int E,
                                                  const int* __restrict__ flag,
                                                  int* __restrict__ M,
                                                  int NBUCK, int NCHUNK) {
  __shared__ int h[256];
  int tid = threadIdx.x;
  h[tid] = 0;
  __syncthreads();
  int is64 = flag[0];
  int base = blockIdx.x * CHUNK;
  int end = min(base + CHUNK, E);
  if (is64) {
    const long long* p = (const long long*)ei;
    for (int i = base + tid; i < end; i += 256)
      atomicAdd(&h[((int)p[(size_t)E + i]) >> 8], 1);
  } else {
    const int* p = (const int*)ei;
    for (int i = base + tid; i < end; i += 256)
      atomicAdd(&h[p[(size_t)E + i] >> 8], 1);
  }
  __syncthreads();
  if (tid < NBUCK) M[tid * NCHUNK + blockIdx.x] = h[tid];
}

// ---------------------------------------------------------------- matscanA:
// one block per bucket: parallel exclusive scan of that bucket's chunk row.
__global__ __launch_bounds__(256) void matscanA_kernel(int* __restrict__ M,
                                                       int* __restrict__ btot,
                                                       int NCHUNK) {
  __shared__ int s[256];
  int tid = threadIdx.x;
  int b = blockIdx.x;
  int v = (tid < NCHUNK) ? M[b * NCHUNK + tid] : 0;
  s[tid] = v;
  __syncthreads();
  for (int d = 1; d < 256; d <<= 1) {
    int add = (tid >= d) ? s[tid - d] : 0;
    __syncthreads();
    s[tid] += add;
    __syncthreads();
  }
  if (tid < NCHUNK) M[b * NCHUNK + tid] = s[tid] - v;  // exclusive
  if (tid == 255) btot[b] = s[255];
}

// ---------------------------------------------------------------- matscanB:
// single block: exclusive scan of bucket totals -> bstart.
__global__ __launch_bounds__(256) void matscanB_kernel(
    const int* __restrict__ btot, int* __restrict__ bstart, int NBUCK, int E) {
  __shared__ int s[256];
  int tid = threadIdx.x;
  int v = (tid < NBUCK) ? btot[tid] : 0;
  s[tid] = v;
  __syncthreads();
  for (int d = 1; d < 256; d <<= 1) {
    int add = (tid >= d) ? s[tid - d] : 0;
    __syncthreads();
    s[tid] += add;
    __syncthreads();
  }
  if (tid < NBUCK) bstart[tid] = s[tid] - v;
  if (tid == 0) bstart[NBUCK] = E;
}

// ---------------------------------------------------------------- pass 1c:
// scatter packed (src<<16|c) into exact per-(chunk,bucket) staging slots.
// Ranks via LDS atomics; every block writes a disjoint dense region.
__global__ __launch_bounds__(256) void p1c_kernel(
    const void* __restrict__ ei, int E, const int* __restrict__ flag,
    const int* __restrict__ M, const int* __restrict__ bstart, int NBUCK,
    int NCHUNK, unsigned int* __restrict__ staging) {
  __shared__ int rowM[256];
  __shared__ int lcur[256];
  int tid = threadIdx.x;
  if (tid < NBUCK) rowM[tid] = M[tid * NCHUNK + blockIdx.x] + bstart[tid];
  lcur[tid] = 0;
  __syncthreads();
  int is64 = flag[0];
  int base = blockIdx.x * CHUNK;
  int end = min(base + CHUNK, E);
  for (int i = base + tid; i < end; i += 256) {
    int src, c;
    if (is64) {
      const long long* p = (const long long*)ei;
      src = (int)p[i];
      c = (int)p[(size_t)E + i];
    } else {
      const int* p = (const int*)ei;
      src = p[i];
      c = p[(size_t)E + i];
    }
    int b = c >> 8;
    int r = atomicAdd(&lcur[b], 1);
    staging[rowM[b] + r] = ((unsigned int)src << 16) | (unsigned int)c;
  }
}

// ---------------------------------------------------------------- pass 2:
// one block per bucket: LDS histogram + scan of the 256 nodes, emit
// off/cnt/dis densely, scatter srcs (ushort) into the bucket's CSR window.
__global__ __launch_bounds__(256) void p2_kernel(
    const unsigned int* __restrict__ staging, const int* __restrict__ bstart,
    int* __restrict__ off, int* __restrict__ cnt, float* __restrict__ dis,
    unsigned short* __restrict__ srcs, int n) {
  __shared__ int h[256], ex[256], lcur[256];
  __shared__ unsigned int lst[LSTCAP];
  int tid = threadIdx.x;
  int b = blockIdx.x;
  int base = bstart[b];
  int len = bstart[b + 1] - base;
  h[tid] = 0;
  lcur[tid] = 0;
  __syncthreads();
  for (int i = tid; i < len; i += 256) {
    unsigned int v = staging[base + i];
    if (i < LSTCAP) lst[i] = v;
    atomicAdd(&h[v & 255u], 1);
  }
  __syncthreads();
  int my = h[tid];
  ex[tid] = my;
  __syncthreads();
  for (int d = 1; d < 256; d <<= 1) {
    int add = (tid >= d) ? ex[tid - d] : 0;
    __syncthreads();
    ex[tid] += add;
    __syncthreads();
  }
  int excl = ex[tid] - my;  // exclusive within bucket
  ex[tid] = excl;
  int node = (b << 8) + tid;
  if (node < n) {
    off[node] = base + excl;
    cnt[node] = my;
    dis[node] = rsqrtf((float)(my + 1));  // deg incl self loop >= 1
  }
  __syncthreads();
  for (int i = tid; i < len; i += 256) {
    unsigned int v = (i < LSTCAP) ? lst[i] : staging[base + i];
    int ci = (int)(v & 255u);
    int r = atomicAdd(&lcur[ci], 1);
    srcs[base + ex[ci] + r] = (unsigned short)(v >> 16);
  }
}

// ---------------------------------------------------------------- MFMA GEMM, fp32 A (split hi/lo, 3 MFMA)
// G_bf16[n x 128] = dis[row] * (A_f32[n x 128] @ W[128 x 128])
__global__ __launch_bounds__(256, 8) void gemm_f32_kernel(
    const float* __restrict__ A, const unsigned short* __restrict__ wfrag,
    const float* __restrict__ dis, unsigned short* __restrict__ G, int n) {
  __shared__ unsigned short Ah[2][4][64][8];
  __shared__ unsigned short Al[2][4][64][8];
  __shared__ float disS[32];
  int tid = threadIdx.x;
  int row0 = blockIdx.x * 32;

  if (tid < 32) {
    int gr = row0 + tid;
    disS[tid] = (gr < n) ? dis[gr] : 0.f;
  }

  const float4* A4 = (const float4*)A;
#pragma unroll
  for (int it = 0; it < 4; ++it) {
    int fi = it * 256 + tid;
    int row = fi >> 5;          // 0..31
    int c4 = fi & 31;           // float4 index along k
    int gr = row0 + row;
    float4 v = make_float4(0.f, 0.f, 0.f, 0.f);
    if (gr < n) v = A4[(size_t)gr * 32 + c4];
    unsigned short h0 = f2bf(v.x), h1 = f2bf(v.y), h2 = f2bf(v.z), h3 = f2bf(v.w);
    unsigned short l0 = f2bf(v.x - bf2f(h0)), l1 = f2bf(v.y - bf2f(h1));
    unsigned short l2 = f2bf(v.z - bf2f(h2)), l3 = f2bf(v.w - bf2f(h3));
    int band = row >> 4;
    int kslab = c4 >> 3;
    int lane = ((c4 >> 1) & 3) * 16 + (row & 15);
    int e0 = (c4 & 1) * 4;
    *(uint2*)&Ah[band][kslab][lane][e0] =
        make_uint2((unsigned int)h0 | ((unsigned int)h1 << 16),
                   (unsigned int)h2 | ((unsigned int)h3 << 16));
    *(uint2*)&Al[band][kslab][lane][e0] =
        make_uint2((unsigned int)l0 | ((unsigned int)l1 << 16),
                   (unsigned int)l2 | ((unsigned int)l3 << 16));
  }
  __syncthreads();

  int w = tid >> 6, lane = tid & 63;
  int band = w & 1, ch = w >> 1;

  f32x4 acc[4];
#pragma unroll
  for (int t = 0; t < 4; ++t) acc[t] = (f32x4){0.f, 0.f, 0.f, 0.f};

#pragma unroll
  for (int ks = 0; ks < 4; ++ks) {
    bf16x8 ahi = *(const bf16x8*)&Ah[band][ks][lane][0];
    bf16x8 alo = *(const bf16x8*)&Al[band][ks][lane][0];
#pragma unroll
    for (int ct = 0; ct < 4; ++ct) {
      size_t fb = ((size_t)(ks * 8 + ch * 4 + ct) * 64 + lane) * 8;
      bf16x8 whi = *(const bf16x8*)&wfrag[fb];
      bf16x8 wlo = *(const bf16x8*)&wfrag[16384 + fb];
      acc[ct] = __builtin_amdgcn_mfma_f32_16x16x32_bf16(ahi, whi, acc[ct], 0, 0, 0);
      acc[ct] = __builtin_amdgcn_mfma_f32_16x16x32_bf16(ahi, wlo, acc[ct], 0, 0, 0);
      acc[ct] = __builtin_amdgcn_mfma_f32_16x16x32_bf16(alo, whi, acc[ct], 0, 0, 0);
    }
  }

#pragma unroll
  for (int ct = 0; ct < 4; ++ct) {
    int col = ch * 64 + ct * 16 + (lane & 15);
#pragma unroll
    for (int r = 0; r < 4; ++r) {
      int lrow = band * 16 + ((lane >> 4) << 2) + r;
      int grow = row0 + lrow;
      if (grow < n) G[(size_t)grow * DF + col] = f2bf(acc[ct][r] * disS[lrow]);
    }
  }
}

// ---------------------------------------------------------------- MFMA GEMM, bf16 A (2 MFMA)
__global__ __launch_bounds__(256, 8) void gemm_bf16_kernel(
    const unsigned short* __restrict__ A, const unsigned short* __restrict__ wfrag,
    const float* __restrict__ dis, unsigned short* __restrict__ G, int n) {
  __shared__ unsigned short Ah[2][4][64][8];
  __shared__ float disS[32];
  int tid = threadIdx.x;
  int row0 = blockIdx.x * 32;

  if (tid < 32) {
    int gr = row0 + tid;
    disS[tid] = (gr < n) ? dis[gr] : 0.f;
  }

  const uint4* A4 = (const uint4*)A;  // 8 bf16 per uint4
#pragma unroll
  for (int it = 0; it < 2; ++it) {
    int fi = it * 256 + tid;    // 0..511
    int row = fi >> 4;          // 0..31
    int m = fi & 15;            // 8-k group
    int gr = row0 + row;
    uint4 v = make_uint4(0u, 0u, 0u, 0u);
    if (gr < n) v = A4[(size_t)gr * 16 + m];
    int band = row >> 4;
    int kslab = m >> 2;
    int lane = (m & 3) * 16 + (row & 15);
    *(uint4*)&Ah[band][kslab][lane][0] = v;
  }
  __syncthreads();

  int w = tid >> 6, lane = tid & 63;
  int band = w & 1, ch = w >> 1;

  f32x4 acc[4];
#pragma unroll
  for (int t = 0; t < 4; ++t) acc[t] = (f32x4){0.f, 0.f, 0.f, 0.f};

#pragma unroll
  for (int ks = 0; ks < 4; ++ks) {
    bf16x8 ahi = *(const bf16x8*)&Ah[band][ks][lane][0];
#pragma unroll
    for (int ct = 0; ct < 4; ++ct) {
      size_t fb = ((size_t)(ks * 8 + ch * 4 + ct) * 64 + lane) * 8;
      bf16x8 whi = *(const bf16x8*)&wfrag[fb];
      bf16x8 wlo = *(const bf16x8*)&wfrag[16384 + fb];
      acc[ct] = __builtin_amdgcn_mfma_f32_16x16x32_bf16(ahi, whi, acc[ct], 0, 0, 0);
      acc[ct] = __builtin_amdgcn_mfma_f32_16x16x32_bf16(ahi, wlo, acc[ct], 0, 0, 0);
    }
  }

#pragma unroll
  for (int ct = 0; ct < 4; ++ct) {
    int col = ch * 64 + ct * 16 + (lane & 15);
#pragma unroll
    for (int r = 0; r < 4; ++r) {
      int lrow = band * 16 + ((lane >> 4) << 2) + r;
      int grow = row0 + lrow;
      if (grow < n) G[(size_t)grow * DF + col] = f2bf(acc[ct][r] * disS[lrow]);
    }
  }
}

// ---------------------------------------------------------------- aggregation: one wave per node
// acc = sum_{s in N(t)} g[s] + g[t];  OUT==0: write bf16(dis*acc + b)
//                                     OUT==1: write f32 lrelu(dis*acc + b)
template <int OUT>
__global__ __launch_bounds__(1024) void agg_kernel(
    const unsigned short* __restrict__ g, const unsigned short* __restrict__ srcs,
    const int* __restrict__ off, const int* __restrict__ cnt,
    const float* __restrict__ dis, const float* __restrict__ bias,
    void* __restrict__ outv, int n) {
  int wid = (blockIdx.x * blockDim.x + threadIdx.x) >> 6;
  int lane = threadIdx.x & 63;
  if (wid >= n) return;

  float diw = dis[wid];
  unsigned int us = ((const unsigned int*)(g + (size_t)wid * DF))[lane];
  float ax = __uint_as_float(us << 16);         // self term g[wid]
  float ay = __uint_as_float(us & 0xFFFF0000u);

  int s = off[wid];
  int e = s + cnt[wid];
  // predicated unroll-16: clamp index to e-1, zero invalid contributions
  for (int j = s; j < e; j += 16) {
    int src[16];
    unsigned int u[16];
#pragma unroll
    for (int q = 0; q < 16; ++q) {
      int idx = j + q;
      src[q] = (int)srcs[idx < e ? idx : e - 1];
    }
#pragma unroll
    for (int q = 0; q < 16; ++q)
      u[q] = ((const unsigned int*)(g + (size_t)src[q] * DF))[lane];
#pragma unroll
    for (int q = 0; q < 16; ++q) {
      bool v = (j + q) < e;
      float vx = __uint_as_float(u[q] << 16);
      float vy = __uint_as_float(u[q] & 0xFFFF0000u);
      ax += v ? vx : 0.f;
      ay += v ? vy : 0.f;
    }
  }

  float2 bb = ((const float2*)bias)[lane];
  ax = fmaf(ax, diw, bb.x);
  ay = fmaf(ay, diw, bb.y);
  if (OUT == 0) {
    unsigned int pack =
        (unsigned int)f2bf(ax) | ((unsigned int)f2bf(ay) << 16);
    ((unsigned int*)((unsigned short*)outv + (size_t)wid * DF))[lane] = pack;
  } else {
    float2 r;
    r.x = lrelu(ax);
    r.y = lrelu(ay);
    ((float2*)((float*)outv + (size_t)wid * DF))[lane] = r;
  }
}

// ---------------------------------------------------------------- launch
extern "C" void kernel_launch(void* const* d_in, const int* in_sizes, int n_in,
                              void* d_out, int out_size, void* d_ws, size_t ws_size,
                              hipStream_t stream) {
  const float* x  = (const float*)d_in[0];
  const void*  ei = d_in[1];
  const float* W1 = (const float*)d_in[2];
  const float* b1 = (const float*)d_in[3];
  const float* W2 = (const float*)d_in[4];
  const float* b2 = (const float*)d_in[5];
  float* out = (float*)d_out;

  int n = in_sizes[0] / DF;  // 50000
  int E = in_sizes[1] / 2;   // 800000
  int NBUCK = (n + 255) >> 8;              // 196
  int NCHUNK = (E + CHUNK - 1) / CHUNK;    // 196

  // workspace carve (16B aligned)
  char* w = (char*)d_ws;
  auto carve = [&](size_t bytes) {
    char* p = w;
    w += (bytes + 15) & ~(size_t)15;
    return p;
  };
  float* dis    = (float*)carve((size_t)n * 4);
  int*   cnt    = (int*)carve((size_t)n * 4);
  int*   off    = (int*)carve((size_t)n * 4);
  int*   flag   = (int*)carve(16);
  int*   bstart = (int*)carve((size_t)(NBUCK + 1) * 4);
  int*   btot   = (int*)carve((size_t)NBUCK * 4);
  int*   M      = (int*)carve((size_t)NCHUNK * NBUCK * 4);
  unsigned short* wfrag = (unsigned short*)carve(65536 * 2);  // 2 x (hi+lo)
  unsigned int* staging = (unsigned int*)carve((size_t)E * 4);
  unsigned short* srcs  = (unsigned short*)carve((size_t)E * 2);
  unsigned short* bufG  = (unsigned short*)carve((size_t)n * DF * 2);
  unsigned short* bufH  = (unsigned short*)carve((size_t)n * DF * 2);

  // CSR build: exact counting sort by bucket = target>>8 (no global atomics)
  prep_kernel<<<3, 256, 0, stream>>>(W1, W2, wfrag, (const unsigned int*)ei, E, flag);
  p1a_kernel<<<NCHUNK, 256, 0, stream>>>(ei, E, flag, M, NBUCK, NCHUNK);
  matscanA_kernel<<<NBUCK, 256, 0, stream>>>(M, btot, NCHUNK);
  matscanB_kernel<<<1, 256, 0, stream>>>(btot, bstart, NBUCK, E);
  p1c_kernel<<<NCHUNK, 256, 0, stream>>>(ei, E, flag, M, bstart, NBUCK, NCHUNK,
                                         staging);
  p2_kernel<<<NBUCK, 256, 0, stream>>>(staging, bstart, off, cnt, dis, srcs, n);

  int gGemm = (n + 31) / 32;        // 1563
  int gAgg  = (n + 15) / 16;        // 3125 (16 waves/block)

  // layer 1: g1 = dis * bf16(x @ W1) ; h1 = bf16(dis*(sum g1 + g1_self) + b1)
  gemm_f32_kernel<<<gGemm, 256, 0, stream>>>(x, wfrag, dis, bufG, n);
  agg_kernel<0><<<gAgg, 1024, 0, stream>>>(bufG, srcs, off, cnt, dis, b1, bufH, n);

  // layer 2: g2 = dis * bf16(h1 @ W2) ; out = lrelu(dis*(sum g2 + g2_self) + b2)
  gemm_bf16_kernel<<<gGemm, 256, 0, stream>>>(bufH, wfrag + 32768, dis, bufG, n);
  agg_kernel<1><<<gAgg, 1024, 0, stream>>>(bufG, srcs, off, cnt, dis, b2, out, n);
}

// Round 9
// 172.384 us; speedup vs baseline: 1.5490x; 1.0375x over previous
//
#include <hip/hip_runtime.h>

#define DF 128      // feature dim
#define CHUNK 4096  // edges per chunk in counting sort
#define LSTCAP 6144 // LDS staging cap in p2 (bucket avg ~4096, 32 sigma slack)

typedef __bf16 bf16x8 __attribute__((ext_vector_type(8)));
typedef float f32x4 __attribute__((ext_vector_type(4)));

// NOTE: packing assumes n <= 65536, NBUCK <= 256, NCHUNK <= 256
// (problem fixes n = 50000, E = 800000 -> NBUCK = 196, NCHUNK = 196).

// ---------------------------------------------------------------- utilities
static __device__ __forceinline__ float lrelu(float x) {
  return x > 0.f ? x : 0.1f * x;
}
static __device__ __forceinline__ unsigned short f2bf(float f) {
  unsigned int u = __float_as_uint(f);
  u += 0x7FFFu + ((u >> 16) & 1u);
  return (unsigned short)(u >> 16);
}
static __device__ __forceinline__ float bf2f(unsigned short h) {
  return __uint_as_float((unsigned int)h << 16);
}

// ---------------------------------------------------------------- prep:
// blocks 0,1: split W1/W2 into bf16 hi/lo in MFMA B-fragment-linear order.
// block 2: detect int64 vs int32 edge_index.
__global__ void prep_kernel(const float* __restrict__ W1,
                            const float* __restrict__ W2,
                            unsigned short* __restrict__ wfrag,
                            const unsigned int* __restrict__ ei_u, int E,
                            int* __restrict__ flag) {
  if (blockIdx.x == 2) {
    __shared__ int any32;
    if (threadIdx.x == 0) any32 = 0;
    __syncthreads();
    long long idx = (long long)threadIdx.x * (E / 256);
    if (idx < E) {
      if (ei_u[2 * idx + 1] != 0u) any32 = 1;
    }
    __syncthreads();
    if (threadIdx.x == 0) flag[0] = any32 ? 0 : 1;  // 1 => int64
    return;
  }
  const float* W = (blockIdx.x == 0) ? W1 : W2;
  unsigned short* hi = wfrag + (size_t)blockIdx.x * 32768;
  unsigned short* lo = hi + 16384;
  for (int i = threadIdx.x; i < 16384; i += 256) {
    int k = i >> 7, c = i & 127;
    float w = W[i];
    unsigned short h = f2bf(w);
    unsigned short l = f2bf(w - bf2f(h));
    int fid = (((k >> 5) * 8) + (c >> 4)) * 64 + ((k >> 3) & 3) * 16 + (c & 15);
    int pos = fid * 8 + (k & 7);
    hi[pos] = h;
    lo[pos] = l;
  }
}

// ---------------------------------------------------------------- pass 1a:
// per-chunk bucket histogram (bucket = target >> 8), LDS only.
// M stored TRANSPOSED: M[bucket * NCHUNK + chunk].
__global__ __launch_bounds__(256) void p1a_kernel(const void* __restrict__ ei,
                                                  int E,
                                                  const int* __restrict__ flag,
                                                  int* __restrict__ M,
                                                  int NBUCK, int NCHUNK) {
  __shared__ int h[256];
  int tid = threadIdx.x;
  h[tid] = 0;
  __syncthreads();
  int is64 = flag[0];
  int base = blockIdx.x * CHUNK;
  int end = min(base + CHUNK, E);
  if (is64) {
    const long long* p = (const long long*)ei;
    for (int i = base + tid; i < end; i += 256)
      atomicAdd(&h[((int)p[(size_t)E + i]) >> 8], 1);
  } else {
    const int* p = (const int*)ei;
    for (int i = base + tid; i < end; i += 256)
      atomicAdd(&h[p[(size_t)E + i] >> 8], 1);
  }
  __syncthreads();
  if (tid < NBUCK) M[tid * NCHUNK + blockIdx.x] = h[tid];
}

// ---------------------------------------------------------------- matscanA:
// one block per bucket: parallel exclusive scan of that bucket's chunk row.
__global__ __launch_bounds__(256) void matscanA_kernel(int* __restrict__ M,
                                                       int* __restrict__ btot,
                                                       int NCHUNK) {
  __shared__ int s[256];
  int tid = threadIdx.x;
  int b = blockIdx.x;
  int v = (tid < NCHUNK) ? M[b * NCHUNK + tid] : 0;
  s[tid] = v;
  __syncthreads();
  for (int d = 1; d < 256; d <<= 1) {
    int add = (tid >= d) ? s[tid - d] : 0;
    __syncthreads();
    s[tid] += add;
    __syncthreads();
  }
  if (tid < NCHUNK) M[b * NCHUNK + tid] = s[tid] - v;  // exclusive
  if (tid == 255) btot[b] = s[255];
}

// ---------------------------------------------------------------- matscanB:
// single block: exclusive scan of bucket totals -> bstart.
__global__ __launch_bounds__(256) void matscanB_kernel(
    const int* __restrict__ btot, int* __restrict__ bstart, int NBUCK, int E) {
  __shared__ int s[256];
  int tid = threadIdx.x;
  int v = (tid < NBUCK) ? btot[tid] : 0;
  s[tid] = v;
  __syncthreads();
  for (int d = 1; d < 256; d <<= 1) {
    int add = (tid >= d) ? s[tid - d] : 0;
    __syncthreads();
    s[tid] += add;
    __syncthreads();
  }
  if (tid < NBUCK) bstart[tid] = s[tid] - v;
  if (tid == 0) bstart[NBUCK] = E;
}

// ---------------------------------------------------------------- pass 1c:
// scatter packed (src<<16|c) into exact per-(chunk,bucket) staging slots.
// Ranks via LDS atomics; every block writes a disjoint dense region.
__global__ __launch_bounds__(256) void p1c_kernel(
    const void* __restrict__ ei, int E, const int* __restrict__ flag,
    const int* __restrict__ M, const int* __restrict__ bstart, int NBUCK,
    int NCHUNK, unsigned int* __restrict__ staging) {
  __shared__ int rowM[256];
  __shared__ int lcur[256];
  int tid = threadIdx.x;
  if (tid < NBUCK) rowM[tid] = M[tid * NCHUNK + blockIdx.x] + bstart[tid];
  lcur[tid] = 0;
  __syncthreads();
  int is64 = flag[0];
  int base = blockIdx.x * CHUNK;
  int end = min(base + CHUNK, E);
  for (int i = base + tid; i < end; i += 256) {
    int src, c;
    if (is64) {
      const long long* p = (const long long*)ei;
      src = (int)p[i];
      c = (int)p[(size_t)E + i];
    } else {
      const int* p = (const int*)ei;
      src = p[i];
      c = p[(size_t)E + i];
    }
    int b = c >> 8;
    int r = atomicAdd(&lcur[b], 1);
    staging[rowM[b] + r] = ((unsigned int)src << 16) | (unsigned int)c;
  }
}

// ---------------------------------------------------------------- pass 2:
// one block per bucket: LDS histogram + scan of the 256 nodes, emit
// off/cnt/dis densely, scatter srcs (ushort) into the bucket's CSR window.
__global__ __launch_bounds__(256) void p2_kernel(
    const unsigned int* __restrict__ staging, const int* __restrict__ bstart,
    int* __restrict__ off, int* __restrict__ cnt, float* __restrict__ dis,
    unsigned short* __restrict__ srcs, int n) {
  __shared__ int h[256], ex[256], lcur[256];
  __shared__ unsigned int lst[LSTCAP];
  int tid = threadIdx.x;
  int b = blockIdx.x;
  int base = bstart[b];
  int len = bstart[b + 1] - base;
  h[tid] = 0;
  lcur[tid] = 0;
  __syncthreads();
  for (int i = tid; i < len; i += 256) {
    unsigned int v = staging[base + i];
    if (i < LSTCAP) lst[i] = v;
    atomicAdd(&h[v & 255u], 1);
  }
  __syncthreads();
  int my = h[tid];
  ex[tid] = my;
  __syncthreads();
  for (int d = 1; d < 256; d <<= 1) {
    int add = (tid >= d) ? ex[tid - d] : 0;
    __syncthreads();
    ex[tid] += add;
    __syncthreads();
  }
  int excl = ex[tid] - my;  // exclusive within bucket
  ex[tid] = excl;
  int node = (b << 8) + tid;
  if (node < n) {
    off[node] = base + excl;
    cnt[node] = my;
    dis[node] = rsqrtf((float)(my + 1));  // deg incl self loop >= 1
  }
  __syncthreads();
  for (int i = tid; i < len; i += 256) {
    unsigned int v = (i < LSTCAP) ? lst[i] : staging[base + i];
    int ci = (int)(v & 255u);
    int r = atomicAdd(&lcur[ci], 1);
    srcs[base + ex[ci] + r] = (unsigned short)(v >> 16);
  }
}

// ---------------------------------------------------------------- MFMA GEMM, fp32 A (split hi/lo, 3 MFMA)
// G_bf16[n x 128] = dis[row] * (A_f32[n x 128] @ W[128 x 128])
__global__ __launch_bounds__(256, 8) void gemm_f32_kernel(
    const float* __restrict__ A, const unsigned short* __restrict__ wfrag,
    const float* __restrict__ dis, unsigned short* __restrict__ G, int n) {
  __shared__ unsigned short Ah[2][4][64][8];
  __shared__ unsigned short Al[2][4][64][8];
  __shared__ float disS[32];
  int tid = threadIdx.x;
  int row0 = blockIdx.x * 32;

  if (tid < 32) {
    int gr = row0 + tid;
    disS[tid] = (gr < n) ? dis[gr] : 0.f;
  }

  const float4* A4 = (const float4*)A;
#pragma unroll
  for (int it = 0; it < 4; ++it) {
    int fi = it * 256 + tid;
    int row = fi >> 5;          // 0..31
    int c4 = fi & 31;           // float4 index along k
    int gr = row0 + row;
    float4 v = make_float4(0.f, 0.f, 0.f, 0.f);
    if (gr < n) v = A4[(size_t)gr * 32 + c4];
    unsigned short h0 = f2bf(v.x), h1 = f2bf(v.y), h2 = f2bf(v.z), h3 = f2bf(v.w);
    unsigned short l0 = f2bf(v.x - bf2f(h0)), l1 = f2bf(v.y - bf2f(h1));
    unsigned short l2 = f2bf(v.z - bf2f(h2)), l3 = f2bf(v.w - bf2f(h3));
    int band = row >> 4;
    int kslab = c4 >> 3;
    int lane = ((c4 >> 1) & 3) * 16 + (row & 15);
    int e0 = (c4 & 1) * 4;
    *(uint2*)&Ah[band][kslab][lane][e0] =
        make_uint2((unsigned int)h0 | ((unsigned int)h1 << 16),
                   (unsigned int)h2 | ((unsigned int)h3 << 16));
    *(uint2*)&Al[band][kslab][lane][e0] =
        make_uint2((unsigned int)l0 | ((unsigned int)l1 << 16),
                   (unsigned int)l2 | ((unsigned int)l3 << 16));
  }
  __syncthreads();

  int w = tid >> 6, lane = tid & 63;
  int band = w & 1, ch = w >> 1;

  f32x4 acc[4];
#pragma unroll
  for (int t = 0; t < 4; ++t) acc[t] = (f32x4){0.f, 0.f, 0.f, 0.f};

#pragma unroll
  for (int ks = 0; ks < 4; ++ks) {
    bf16x8 ahi = *(const bf16x8*)&Ah[band][ks][lane][0];
    bf16x8 alo = *(const bf16x8*)&Al[band][ks][lane][0];
#pragma unroll
    for (int ct = 0; ct < 4; ++ct) {
      size_t fb = ((size_t)(ks * 8 + ch * 4 + ct) * 64 + lane) * 8;
      bf16x8 whi = *(const bf16x8*)&wfrag[fb];
      bf16x8 wlo = *(const bf16x8*)&wfrag[16384 + fb];
      acc[ct] = __builtin_amdgcn_mfma_f32_16x16x32_bf16(ahi, whi, acc[ct], 0, 0, 0);
      acc[ct] = __builtin_amdgcn_mfma_f32_16x16x32_bf16(ahi, wlo, acc[ct], 0, 0, 0);
      acc[ct] = __builtin_amdgcn_mfma_f32_16x16x32_bf16(alo, whi, acc[ct], 0, 0, 0);
    }
  }

#pragma unroll
  for (int ct = 0; ct < 4; ++ct) {
    int col = ch * 64 + ct * 16 + (lane & 15);
#pragma unroll
    for (int r = 0; r < 4; ++r) {
      int lrow = band * 16 + ((lane >> 4) << 2) + r;
      int grow = row0 + lrow;
      if (grow < n) G[(size_t)grow * DF + col] = f2bf(acc[ct][r] * disS[lrow]);
    }
  }
}

// ---------------------------------------------------------------- MFMA GEMM, bf16 A (2 MFMA)
__global__ __launch_bounds__(256, 8) void gemm_bf16_kernel(
    const unsigned short* __restrict__ A, const unsigned short* __restrict__ wfrag,
    const float* __restrict__ dis, unsigned short* __restrict__ G, int n) {
  __shared__ unsigned short Ah[2][4][64][8];
  __shared__ float disS[32];
  int tid = threadIdx.x;
  int row0 = blockIdx.x * 32;

  if (tid < 32) {
    int gr = row0 + tid;
    disS[tid] = (gr < n) ? dis[gr] : 0.f;
  }

  const uint4* A4 = (const uint4*)A;  // 8 bf16 per uint4
#pragma unroll
  for (int it = 0; it < 2; ++it) {
    int fi = it * 256 + tid;    // 0..511
    int row = fi >> 4;          // 0..31
    int m = fi & 15;            // 8-k group
    int gr = row0 + row;
    uint4 v = make_uint4(0u, 0u, 0u, 0u);
    if (gr < n) v = A4[(size_t)gr * 16 + m];
    int band = row >> 4;
    int kslab = m >> 2;
    int lane = (m & 3) * 16 + (row & 15);
    *(uint4*)&Ah[band][kslab][lane][0] = v;
  }
  __syncthreads();

  int w = tid >> 6, lane = tid & 63;
  int band = w & 1, ch = w >> 1;

  f32x4 acc[4];
#pragma unroll
  for (int t = 0; t < 4; ++t) acc[t] = (f32x4){0.f, 0.f, 0.f, 0.f};

#pragma unroll
  for (int ks = 0; ks < 4; ++ks) {
    bf16x8 ahi = *(const bf16x8*)&Ah[band][ks][lane][0];
#pragma unroll
    for (int ct = 0; ct < 4; ++ct) {
      size_t fb = ((size_t)(ks * 8 + ch * 4 + ct) * 64 + lane) * 8;
      bf16x8 whi = *(const bf16x8*)&wfrag[fb];
      bf16x8 wlo = *(const bf16x8*)&wfrag[16384 + fb];
      acc[ct] = __builtin_amdgcn_mfma_f32_16x16x32_bf16(ahi, whi, acc[ct], 0, 0, 0);
      acc[ct] = __builtin_amdgcn_mfma_f32_16x16x32_bf16(ahi, wlo, acc[ct], 0, 0, 0);
    }
  }

#pragma unroll
  for (int ct = 0; ct < 4; ++ct) {
    int col = ch * 64 + ct * 16 + (lane & 15);
#pragma unroll
    for (int r = 0; r < 4; ++r) {
      int lrow = band * 16 + ((lane >> 4) << 2) + r;
      int grow = row0 + lrow;
      if (grow < n) G[(size_t)grow * DF + col] = f2bf(acc[ct][r] * disS[lrow]);
    }
  }
}

// ---------------------------------------------------------------- aggregation
// wave per node; 2 edge-slots (lanes 0-31 = edge j, 32-63 = edge j+1);
// each lane gathers uint2 (4 bf16 cols); unroll 4 -> 8 gathers in flight.
// acc = sum_{s in N(t)} g[s] + g[t];  OUT==0: write bf16(dis*acc + b)
//                                     OUT==1: write f32 lrelu(dis*acc + b)
template <int OUT>
__global__ __launch_bounds__(512) void agg_kernel(
    const unsigned short* __restrict__ g, const unsigned short* __restrict__ srcs,
    const int* __restrict__ off, const int* __restrict__ cnt,
    const float* __restrict__ dis, const float* __restrict__ bias,
    void* __restrict__ outv, int n) {
  int wid = (blockIdx.x * blockDim.x + threadIdx.x) >> 6;
  int lane = threadIdx.x & 63;
  if (wid >= n) return;
  int slot = lane >> 5;   // 0 or 1
  int cp = lane & 31;     // uint2 index: cols 4cp..4cp+3

  float a0 = 0.f, a1 = 0.f, a2 = 0.f, a3 = 0.f;
  if (slot == 0) {  // self term g[wid] (added once)
    uint2 sv = ((const uint2*)(g + (size_t)wid * DF))[cp];
    a0 = __uint_as_float(sv.x << 16);
    a1 = __uint_as_float(sv.x & 0xFFFF0000u);
    a2 = __uint_as_float(sv.y << 16);
    a3 = __uint_as_float(sv.y & 0xFFFF0000u);
  }

  int s = off[wid];
  int e = s + cnt[wid];
  int m8 = s + (((e - s) >> 3) << 3);
  int jb = s;
  for (; jb < m8; jb += 8) {  // exact unroll: 4 iters x 2 slots
    int sc[4];
    uint2 u[4];
#pragma unroll
    for (int k = 0; k < 4; ++k) sc[k] = (int)srcs[jb + 2 * k + slot];
#pragma unroll
    for (int k = 0; k < 4; ++k)
      u[k] = ((const uint2*)(g + (size_t)sc[k] * DF))[cp];
#pragma unroll
    for (int k = 0; k < 4; ++k) {
      a0 += __uint_as_float(u[k].x << 16);
      a1 += __uint_as_float(u[k].x & 0xFFFF0000u);
      a2 += __uint_as_float(u[k].y << 16);
      a3 += __uint_as_float(u[k].y & 0xFFFF0000u);
    }
  }
  for (; jb + 2 <= e; jb += 2) {  // pair steps
    int sc = (int)srcs[jb + slot];
    uint2 u = ((const uint2*)(g + (size_t)sc * DF))[cp];
    a0 += __uint_as_float(u.x << 16);
    a1 += __uint_as_float(u.x & 0xFFFF0000u);
    a2 += __uint_as_float(u.y << 16);
    a3 += __uint_as_float(u.y & 0xFFFF0000u);
  }
  if (jb < e && slot == 0) {  // final odd edge
    int sc = (int)srcs[jb];
    uint2 u = ((const uint2*)(g + (size_t)sc * DF))[cp];
    a0 += __uint_as_float(u.x << 16);
    a1 += __uint_as_float(u.x & 0xFFFF0000u);
    a2 += __uint_as_float(u.y << 16);
    a3 += __uint_as_float(u.y & 0xFFFF0000u);
  }

  // combine the two slots (lane L <-> L^32 hold same cols)
  a0 += __shfl_xor(a0, 32, 64);
  a1 += __shfl_xor(a1, 32, 64);
  a2 += __shfl_xor(a2, 32, 64);
  a3 += __shfl_xor(a3, 32, 64);

  if (slot == 0) {
    float diw = dis[wid];
    float4 bb = ((const float4*)bias)[cp];
    a0 = fmaf(a0, diw, bb.x);
    a1 = fmaf(a1, diw, bb.y);
    a2 = fmaf(a2, diw, bb.z);
    a3 = fmaf(a3, diw, bb.w);
    if (OUT == 0) {
      uint2 p;
      p.x = (unsigned int)f2bf(a0) | ((unsigned int)f2bf(a1) << 16);
      p.y = (unsigned int)f2bf(a2) | ((unsigned int)f2bf(a3) << 16);
      ((uint2*)((unsigned short*)outv + (size_t)wid * DF))[cp] = p;
    } else {
      float4 r;
      r.x = lrelu(a0);
      r.y = lrelu(a1);
      r.z = lrelu(a2);
      r.w = lrelu(a3);
      ((float4*)((float*)outv + (size_t)wid * DF))[cp] = r;
    }
  }
}

// ---------------------------------------------------------------- launch
extern "C" void kernel_launch(void* const* d_in, const int* in_sizes, int n_in,
                              void* d_out, int out_size, void* d_ws, size_t ws_size,
                              hipStream_t stream) {
  const float* x  = (const float*)d_in[0];
  const void*  ei = d_in[1];
  const float* W1 = (const float*)d_in[2];
  const float* b1 = (const float*)d_in[3];
  const float* W2 = (const float*)d_in[4];
  const float* b2 = (const float*)d_in[5];
  float* out = (float*)d_out;

  int n = in_sizes[0] / DF;  // 50000
  int E = in_sizes[1] / 2;   // 800000
  int NBUCK = (n + 255) >> 8;              // 196
  int NCHUNK = (E + CHUNK - 1) / CHUNK;    // 196

  // workspace carve (16B aligned)
  char* w = (char*)d_ws;
  auto carve = [&](size_t bytes) {
    char* p = w;
    w += (bytes + 15) & ~(size_t)15;
    return p;
  };
  float* dis    = (float*)carve((size_t)n * 4);
  int*   cnt    = (int*)carve((size_t)n * 4);
  int*   off    = (int*)carve((size_t)n * 4);
  int*   flag   = (int*)carve(16);
  int*   bstart = (int*)carve((size_t)(NBUCK + 1) * 4);
  int*   btot   = (int*)carve((size_t)NBUCK * 4);
  int*   M      = (int*)carve((size_t)NCHUNK * NBUCK * 4);
  unsigned short* wfrag = (unsigned short*)carve(65536 * 2);  // 2 x (hi+lo)
  unsigned int* staging = (unsigned int*)carve((size_t)E * 4);
  unsigned short* srcs  = (unsigned short*)carve((size_t)E * 2);
  unsigned short* bufG  = (unsigned short*)carve((size_t)n * DF * 2);
  unsigned short* bufH  = (unsigned short*)carve((size_t)n * DF * 2);

  // CSR build: exact counting sort by bucket = target>>8 (no global atomics)
  prep_kernel<<<3, 256, 0, stream>>>(W1, W2, wfrag, (const unsigned int*)ei, E, flag);
  p1a_kernel<<<NCHUNK, 256, 0, stream>>>(ei, E, flag, M, NBUCK, NCHUNK);
  matscanA_kernel<<<NBUCK, 256, 0, stream>>>(M, btot, NCHUNK);
  matscanB_kernel<<<1, 256, 0, stream>>>(btot, bstart, NBUCK, E);
  p1c_kernel<<<NCHUNK, 256, 0, stream>>>(ei, E, flag, M, bstart, NBUCK, NCHUNK,
                                         staging);
  p2_kernel<<<NBUCK, 256, 0, stream>>>(staging, bstart, off, cnt, dis, srcs, n);

  int gGemm = (n + 31) / 32;        // 1563
  int gAgg  = (n + 7) / 8;          // 6250 (8 waves/block)

  // layer 1: g1 = dis * bf16(x @ W1) ; h1 = bf16(dis*(sum g1 + g1_self) + b1)
  gemm_f32_kernel<<<gGemm, 256, 0, stream>>>(x, wfrag, dis, bufG, n);
  agg_kernel<0><<<gAgg, 512, 0, stream>>>(bufG, srcs, off, cnt, dis, b1, bufH, n);

  // layer 2: g2 = dis * bf16(h1 @ W2) ; out = lrelu(dis*(sum g2 + g2_self) + b2)
  gemm_bf16_kernel<<<gGemm, 256, 0, stream>>>(bufH, wfrag + 32768, dis, bufG, n);
  agg_kernel<1><<<gAgg, 512, 0, stream>>>(bufG, srcs, off, cnt, dis, b2, out, n);
}

// Round 10
// 169.707 us; speedup vs baseline: 1.5734x; 1.0158x over previous
//
#include <hip/hip_runtime.h>

#define DF 128      // feature dim
#define CHUNK 4096  // edges per chunk in counting sort
#define LSTCAP 6144 // LDS staging cap in p2 (bucket avg ~4096, 32 sigma slack)

typedef __bf16 bf16x8 __attribute__((ext_vector_type(8)));
typedef float f32x4 __attribute__((ext_vector_type(4)));

// NOTE: packing assumes n <= 65536, NBUCK <= 256, NCHUNK <= 256
// (problem fixes n = 50000, E = 800000 -> NBUCK = 196, NCHUNK = 196).

// ---------------------------------------------------------------- utilities
static __device__ __forceinline__ float lrelu(float x) {
  return x > 0.f ? x : 0.1f * x;
}
static __device__ __forceinline__ unsigned short f2bf(float f) {
  unsigned int u = __float_as_uint(f);
  u += 0x7FFFu + ((u >> 16) & 1u);
  return (unsigned short)(u >> 16);
}
static __device__ __forceinline__ float bf2f(unsigned short h) {
  return __uint_as_float((unsigned int)h << 16);
}

// ---------------------------------------------------------------- prep:
// blocks 0,1: split W1/W2 into bf16 hi/lo in MFMA B-fragment-linear order.
// block 2: detect int64 vs int32 edge_index.
__global__ void prep_kernel(const float* __restrict__ W1,
                            const float* __restrict__ W2,
                            unsigned short* __restrict__ wfrag,
                            const unsigned int* __restrict__ ei_u, int E,
                            int* __restrict__ flag) {
  if (blockIdx.x == 2) {
    __shared__ int any32;
    if (threadIdx.x == 0) any32 = 0;
    __syncthreads();
    long long idx = (long long)threadIdx.x * (E / 256);
    if (idx < E) {
      if (ei_u[2 * idx + 1] != 0u) any32 = 1;
    }
    __syncthreads();
    if (threadIdx.x == 0) flag[0] = any32 ? 0 : 1;  // 1 => int64
    return;
  }
  const float* W = (blockIdx.x == 0) ? W1 : W2;
  unsigned short* hi = wfrag + (size_t)blockIdx.x * 32768;
  unsigned short* lo = hi + 16384;
  for (int i = threadIdx.x; i < 16384; i += 256) {
    int k = i >> 7, c = i & 127;
    float w = W[i];
    unsigned short h = f2bf(w);
    unsigned short l = f2bf(w - bf2f(h));
    int fid = (((k >> 5) * 8) + (c >> 4)) * 64 + ((k >> 3) & 3) * 16 + (c & 15);
    int pos = fid * 8 + (k & 7);
    hi[pos] = h;
    lo[pos] = l;
  }
}

// ---------------------------------------------------------------- pass 1a:
// per-chunk bucket histogram (bucket = target >> 8), LDS only.
// M stored TRANSPOSED: M[bucket * NCHUNK + chunk].
__global__ __launch_bounds__(256) void p1a_kernel(const void* __restrict__ ei,
                                                  int E,
                                                  const int* __restrict__ flag,
                                                  int* __restrict__ M,
                                                  int NBUCK, int NCHUNK) {
  __shared__ int h[256];
  int tid = threadIdx.x;
  h[tid] = 0;
  __syncthreads();
  int is64 = flag[0];
  int base = blockIdx.x * CHUNK;
  int end = min(base + CHUNK, E);
  if (is64) {
    const long long* p = (const long long*)ei;
    for (int i = base + tid; i < end; i += 256)
      atomicAdd(&h[((int)p[(size_t)E + i]) >> 8], 1);
  } else {
    const int* p = (const int*)ei;
    for (int i = base + tid; i < end; i += 256)
      atomicAdd(&h[p[(size_t)E + i] >> 8], 1);
  }
  __syncthreads();
  if (tid < NBUCK) M[tid * NCHUNK + blockIdx.x] = h[tid];
}

// ---------------------------------------------------------------- matscanA:
// one block per bucket: parallel exclusive scan of that bucket's chunk row.
__global__ __launch_bounds__(256) void matscanA_kernel(int* __restrict__ M,
                                                       int* __restrict__ btot,
                                                       int NCHUNK) {
  __shared__ int s[256];
  int tid = threadIdx.x;
  int b = blockIdx.x;
  int v = (tid < NCHUNK) ? M[b * NCHUNK + tid] : 0;
  s[tid] = v;
  __syncthreads();
  for (int d = 1; d < 256; d <<= 1) {
    int add = (tid >= d) ? s[tid - d] : 0;
    __syncthreads();
    s[tid] += add;
    __syncthreads();
  }
  if (tid < NCHUNK) M[b * NCHUNK + tid] = s[tid] - v;  // exclusive
  if (tid == 255) btot[b] = s[255];
}

// ---------------------------------------------------------------- matscanB:
// single block: exclusive scan of bucket totals -> bstart.
__global__ __launch_bounds__(256) void matscanB_kernel(
    const int* __restrict__ btot, int* __restrict__ bstart, int NBUCK, int E) {
  __shared__ int s[256];
  int tid = threadIdx.x;
  int v = (tid < NBUCK) ? btot[tid] : 0;
  s[tid] = v;
  __syncthreads();
  for (int d = 1; d < 256; d <<= 1) {
    int add = (tid >= d) ? s[tid - d] : 0;
    __syncthreads();
    s[tid] += add;
    __syncthreads();
  }
  if (tid < NBUCK) bstart[tid] = s[tid] - v;
  if (tid == 0) bstart[NBUCK] = E;
}

// ---------------------------------------------------------------- pass 1c:
// scatter packed (src<<16|c) into exact per-(chunk,bucket) staging slots.
// Ranks via LDS atomics; every block writes a disjoint dense region.
__global__ __launch_bounds__(256) void p1c_kernel(
    const void* __restrict__ ei, int E, const int* __restrict__ flag,
    const int* __restrict__ M, const int* __restrict__ bstart, int NBUCK,
    int NCHUNK, unsigned int* __restrict__ staging) {
  __shared__ int rowM[256];
  __shared__ int lcur[256];
  int tid = threadIdx.x;
  if (tid < NBUCK) rowM[tid] = M[tid * NCHUNK + blockIdx.x] + bstart[tid];
  lcur[tid] = 0;
  __syncthreads();
  int is64 = flag[0];
  int base = blockIdx.x * CHUNK;
  int end = min(base + CHUNK, E);
  for (int i = base + tid; i < end; i += 256) {
    int src, c;
    if (is64) {
      const long long* p = (const long long*)ei;
      src = (int)p[i];
      c = (int)p[(size_t)E + i];
    } else {
      const int* p = (const int*)ei;
      src = p[i];
      c = p[(size_t)E + i];
    }
    int b = c >> 8;
    int r = atomicAdd(&lcur[b], 1);
    staging[rowM[b] + r] = ((unsigned int)src << 16) | (unsigned int)c;
  }
}

// ---------------------------------------------------------------- pass 2:
// one block per bucket: LDS histogram + scan of the 256 nodes, emit
// off/cnt/dis densely, scatter srcs (ushort) into the bucket's CSR window.
__global__ __launch_bounds__(256) void p2_kernel(
    const unsigned int* __restrict__ staging, const int* __restrict__ bstart,
    int* __restrict__ off, int* __restrict__ cnt, float* __restrict__ dis,
    unsigned short* __restrict__ srcs, int n) {
  __shared__ int h[256], ex[256], lcur[256];
  __shared__ unsigned int lst[LSTCAP];
  int tid = threadIdx.x;
  int b = blockIdx.x;
  int base = bstart[b];
  int len = bstart[b + 1] - base;
  h[tid] = 0;
  lcur[tid] = 0;
  __syncthreads();
  for (int i = tid; i < len; i += 256) {
    unsigned int v = staging[base + i];
    if (i < LSTCAP) lst[i] = v;
    atomicAdd(&h[v & 255u], 1);
  }
  __syncthreads();
  int my = h[tid];
  ex[tid] = my;
  __syncthreads();
  for (int d = 1; d < 256; d <<= 1) {
    int add = (tid >= d) ? ex[tid - d] : 0;
    __syncthreads();
    ex[tid] += add;
    __syncthreads();
  }
  int excl = ex[tid] - my;  // exclusive within bucket
  ex[tid] = excl;
  int node = (b << 8) + tid;
  if (node < n) {
    off[node] = base + excl;
    cnt[node] = my;
    dis[node] = rsqrtf((float)(my + 1));  // deg incl self loop >= 1
  }
  __syncthreads();
  for (int i = tid; i < len; i += 256) {
    unsigned int v = (i < LSTCAP) ? lst[i] : staging[base + i];
    int ci = (int)(v & 255u);
    int r = atomicAdd(&lcur[ci], 1);
    srcs[base + ex[ci] + r] = (unsigned short)(v >> 16);
  }
}

// ---------------------------------------------------------------- MFMA GEMM, fp32 A (split hi/lo, 3 MFMA)
// G_bf16[n x 128] = dis[row] * (A_f32[n x 128] @ W[128 x 128])
__global__ __launch_bounds__(256, 8) void gemm_f32_kernel(
    const float* __restrict__ A, const unsigned short* __restrict__ wfrag,
    const float* __restrict__ dis, unsigned short* __restrict__ G, int n) {
  __shared__ unsigned short Ah[2][4][64][8];
  __shared__ unsigned short Al[2][4][64][8];
  __shared__ float disS[32];
  int tid = threadIdx.x;
  int row0 = blockIdx.x * 32;

  if (tid < 32) {
    int gr = row0 + tid;
    disS[tid] = (gr < n) ? dis[gr] : 0.f;
  }

  const float4* A4 = (const float4*)A;
#pragma unroll
  for (int it = 0; it < 4; ++it) {
    int fi = it * 256 + tid;
    int row = fi >> 5;          // 0..31
    int c4 = fi & 31;           // float4 index along k
    int gr = row0 + row;
    float4 v = make_float4(0.f, 0.f, 0.f, 0.f);
    if (gr < n) v = A4[(size_t)gr * 32 + c4];
    unsigned short h0 = f2bf(v.x), h1 = f2bf(v.y), h2 = f2bf(v.z), h3 = f2bf(v.w);
    unsigned short l0 = f2bf(v.x - bf2f(h0)), l1 = f2bf(v.y - bf2f(h1));
    unsigned short l2 = f2bf(v.z - bf2f(h2)), l3 = f2bf(v.w - bf2f(h3));
    int band = row >> 4;
    int kslab = c4 >> 3;
    int lane = ((c4 >> 1) & 3) * 16 + (row & 15);
    int e0 = (c4 & 1) * 4;
    *(uint2*)&Ah[band][kslab][lane][e0] =
        make_uint2((unsigned int)h0 | ((unsigned int)h1 << 16),
                   (unsigned int)h2 | ((unsigned int)h3 << 16));
    *(uint2*)&Al[band][kslab][lane][e0] =
        make_uint2((unsigned int)l0 | ((unsigned int)l1 << 16),
                   (unsigned int)l2 | ((unsigned int)l3 << 16));
  }
  __syncthreads();

  int w = tid >> 6, lane = tid & 63;
  int band = w & 1, ch = w >> 1;

  f32x4 acc[4];
#pragma unroll
  for (int t = 0; t < 4; ++t) acc[t] = (f32x4){0.f, 0.f, 0.f, 0.f};

#pragma unroll
  for (int ks = 0; ks < 4; ++ks) {
    bf16x8 ahi = *(const bf16x8*)&Ah[band][ks][lane][0];
    bf16x8 alo = *(const bf16x8*)&Al[band][ks][lane][0];
#pragma unroll
    for (int ct = 0; ct < 4; ++ct) {
      size_t fb = ((size_t)(ks * 8 + ch * 4 + ct) * 64 + lane) * 8;
      bf16x8 whi = *(const bf16x8*)&wfrag[fb];
      bf16x8 wlo = *(const bf16x8*)&wfrag[16384 + fb];
      acc[ct] = __builtin_amdgcn_mfma_f32_16x16x32_bf16(ahi, whi, acc[ct], 0, 0, 0);
      acc[ct] = __builtin_amdgcn_mfma_f32_16x16x32_bf16(ahi, wlo, acc[ct], 0, 0, 0);
      acc[ct] = __builtin_amdgcn_mfma_f32_16x16x32_bf16(alo, whi, acc[ct], 0, 0, 0);
    }
  }

#pragma unroll
  for (int ct = 0; ct < 4; ++ct) {
    int col = ch * 64 + ct * 16 + (lane & 15);
#pragma unroll
    for (int r = 0; r < 4; ++r) {
      int lrow = band * 16 + ((lane >> 4) << 2) + r;
      int grow = row0 + lrow;
      if (grow < n) G[(size_t)grow * DF + col] = f2bf(acc[ct][r] * disS[lrow]);
    }
  }
}

// ---------------------------------------------------------------- MFMA GEMM, bf16 A (2 MFMA)
__global__ __launch_bounds__(256, 8) void gemm_bf16_kernel(
    const unsigned short* __restrict__ A, const unsigned short* __restrict__ wfrag,
    const float* __restrict__ dis, unsigned short* __restrict__ G, int n) {
  __shared__ unsigned short Ah[2][4][64][8];
  __shared__ float disS[32];
  int tid = threadIdx.x;
  int row0 = blockIdx.x * 32;

  if (tid < 32) {
    int gr = row0 + tid;
    disS[tid] = (gr < n) ? dis[gr] : 0.f;
  }

  const uint4* A4 = (const uint4*)A;  // 8 bf16 per uint4
#pragma unroll
  for (int it = 0; it < 2; ++it) {
    int fi = it * 256 + tid;    // 0..511
    int row = fi >> 4;          // 0..31
    int m = fi & 15;            // 8-k group
    int gr = row0 + row;
    uint4 v = make_uint4(0u, 0u, 0u, 0u);
    if (gr < n) v = A4[(size_t)gr * 16 + m];
    int band = row >> 4;
    int kslab = m >> 2;
    int lane = (m & 3) * 16 + (row & 15);
    *(uint4*)&Ah[band][kslab][lane][0] = v;
  }
  __syncthreads();

  int w = tid >> 6, lane = tid & 63;
  int band = w & 1, ch = w >> 1;

  f32x4 acc[4];
#pragma unroll
  for (int t = 0; t < 4; ++t) acc[t] = (f32x4){0.f, 0.f, 0.f, 0.f};

#pragma unroll
  for (int ks = 0; ks < 4; ++ks) {
    bf16x8 ahi = *(const bf16x8*)&Ah[band][ks][lane][0];
#pragma unroll
    for (int ct = 0; ct < 4; ++ct) {
      size_t fb = ((size_t)(ks * 8 + ch * 4 + ct) * 64 + lane) * 8;
      bf16x8 whi = *(const bf16x8*)&wfrag[fb];
      bf16x8 wlo = *(const bf16x8*)&wfrag[16384 + fb];
      acc[ct] = __builtin_amdgcn_mfma_f32_16x16x32_bf16(ahi, whi, acc[ct], 0, 0, 0);
      acc[ct] = __builtin_amdgcn_mfma_f32_16x16x32_bf16(ahi, wlo, acc[ct], 0, 0, 0);
    }
  }

#pragma unroll
  for (int ct = 0; ct < 4; ++ct) {
    int col = ch * 64 + ct * 16 + (lane & 15);
#pragma unroll
    for (int r = 0; r < 4; ++r) {
      int lrow = band * 16 + ((lane >> 4) << 2) + r;
      int grow = row0 + lrow;
      if (grow < n) G[(size_t)grow * DF + col] = f2bf(acc[ct][r] * disS[lrow]);
    }
  }
}

// ---------------------------------------------------------------- aggregation
// wave per node; 4 edge-slots x 16 lanes; each lane gathers uint4 (8 bf16
// cols) -> one dwordx4 per 16 B, half the memory requests of uint2. Unroll 2
// -> 8 edge-gathers in flight. Combine slots via shfl_xor(16) + shfl_xor(32).
// acc = sum_{s in N(t)} g[s] + g[t];  OUT==0: write bf16(dis*acc + b)
//                                     OUT==1: write f32 lrelu(dis*acc + b)
template <int OUT>
__global__ __launch_bounds__(512) void agg_kernel(
    const unsigned short* __restrict__ g, const unsigned short* __restrict__ srcs,
    const int* __restrict__ off, const int* __restrict__ cnt,
    const float* __restrict__ dis, const float* __restrict__ bias,
    void* __restrict__ outv, int n) {
  int wid = (blockIdx.x * blockDim.x + threadIdx.x) >> 6;
  int lane = threadIdx.x & 63;
  if (wid >= n) return;
  int slot = lane >> 4;   // 0..3
  int cp = lane & 15;     // uint4 index: cols 8cp..8cp+7

  float a0 = 0.f, a1 = 0.f, a2 = 0.f, a3 = 0.f;
  float a4 = 0.f, a5 = 0.f, a6 = 0.f, a7 = 0.f;

#define ACC_U4(U)                                \
  do {                                           \
    a0 += __uint_as_float((U).x << 16);          \
    a1 += __uint_as_float((U).x & 0xFFFF0000u);  \
    a2 += __uint_as_float((U).y << 16);          \
    a3 += __uint_as_float((U).y & 0xFFFF0000u);  \
    a4 += __uint_as_float((U).z << 16);          \
    a5 += __uint_as_float((U).z & 0xFFFF0000u);  \
    a6 += __uint_as_float((U).w << 16);          \
    a7 += __uint_as_float((U).w & 0xFFFF0000u);  \
  } while (0)

  if (slot == 0) {  // self term g[wid] (added once)
    uint4 sv = ((const uint4*)(g + (size_t)wid * DF))[cp];
    ACC_U4(sv);
  }

  int s = off[wid];
  int e = s + cnt[wid];
  int jb = s;
  int m8 = s + (((e - s) >> 3) << 3);
  for (; jb < m8; jb += 8) {  // 2 x 4 slots
    int s0 = (int)srcs[jb + slot];
    int s1 = (int)srcs[jb + 4 + slot];
    uint4 u0 = ((const uint4*)(g + (size_t)s0 * DF))[cp];
    uint4 u1 = ((const uint4*)(g + (size_t)s1 * DF))[cp];
    ACC_U4(u0);
    ACC_U4(u1);
  }
  for (; jb + 4 <= e; jb += 4) {  // 1 x 4 slots
    int s0 = (int)srcs[jb + slot];
    uint4 u0 = ((const uint4*)(g + (size_t)s0 * DF))[cp];
    ACC_U4(u0);
  }
  int rem = e - jb;  // 0..3
  if (slot < rem) {
    int s0 = (int)srcs[jb + slot];
    uint4 u0 = ((const uint4*)(g + (size_t)s0 * DF))[cp];
    ACC_U4(u0);
  }
#undef ACC_U4

  // combine the four slots (lanes L, L^16, L^32, L^48 hold same cols)
  a0 += __shfl_xor(a0, 16, 64); a1 += __shfl_xor(a1, 16, 64);
  a2 += __shfl_xor(a2, 16, 64); a3 += __shfl_xor(a3, 16, 64);
  a4 += __shfl_xor(a4, 16, 64); a5 += __shfl_xor(a5, 16, 64);
  a6 += __shfl_xor(a6, 16, 64); a7 += __shfl_xor(a7, 16, 64);
  a0 += __shfl_xor(a0, 32, 64); a1 += __shfl_xor(a1, 32, 64);
  a2 += __shfl_xor(a2, 32, 64); a3 += __shfl_xor(a3, 32, 64);
  a4 += __shfl_xor(a4, 32, 64); a5 += __shfl_xor(a5, 32, 64);
  a6 += __shfl_xor(a6, 32, 64); a7 += __shfl_xor(a7, 32, 64);

  if (slot == 0) {
    float diw = dis[wid];
    float4 b0 = ((const float4*)bias)[2 * cp];
    float4 b1 = ((const float4*)bias)[2 * cp + 1];
    a0 = fmaf(a0, diw, b0.x);
    a1 = fmaf(a1, diw, b0.y);
    a2 = fmaf(a2, diw, b0.z);
    a3 = fmaf(a3, diw, b0.w);
    a4 = fmaf(a4, diw, b1.x);
    a5 = fmaf(a5, diw, b1.y);
    a6 = fmaf(a6, diw, b1.z);
    a7 = fmaf(a7, diw, b1.w);
    if (OUT == 0) {
      uint4 p;
      p.x = (unsigned int)f2bf(a0) | ((unsigned int)f2bf(a1) << 16);
      p.y = (unsigned int)f2bf(a2) | ((unsigned int)f2bf(a3) << 16);
      p.z = (unsigned int)f2bf(a4) | ((unsigned int)f2bf(a5) << 16);
      p.w = (unsigned int)f2bf(a6) | ((unsigned int)f2bf(a7) << 16);
      ((uint4*)((unsigned short*)outv + (size_t)wid * DF))[cp] = p;
    } else {
      float4 r0, r1;
      r0.x = lrelu(a0); r0.y = lrelu(a1); r0.z = lrelu(a2); r0.w = lrelu(a3);
      r1.x = lrelu(a4); r1.y = lrelu(a5); r1.z = lrelu(a6); r1.w = lrelu(a7);
      ((float4*)((float*)outv + (size_t)wid * DF))[2 * cp] = r0;
      ((float4*)((float*)outv + (size_t)wid * DF))[2 * cp + 1] = r1;
    }
  }
}

// ---------------------------------------------------------------- launch
extern "C" void kernel_launch(void* const* d_in, const int* in_sizes, int n_in,
                              void* d_out, int out_size, void* d_ws, size_t ws_size,
                              hipStream_t stream) {
  const float* x  = (const float*)d_in[0];
  const void*  ei = d_in[1];
  const float* W1 = (const float*)d_in[2];
  const float* b1 = (const float*)d_in[3];
  const float* W2 = (const float*)d_in[4];
  const float* b2 = (const float*)d_in[5];
  float* out = (float*)d_out;

  int n = in_sizes[0] / DF;  // 50000
  int E = in_sizes[1] / 2;   // 800000
  int NBUCK = (n + 255) >> 8;              // 196
  int NCHUNK = (E + CHUNK - 1) / CHUNK;    // 196

  // workspace carve (16B aligned)
  char* w = (char*)d_ws;
  auto carve = [&](size_t bytes) {
    char* p = w;
    w += (bytes + 15) & ~(size_t)15;
    return p;
  };
  float* dis    = (float*)carve((size_t)n * 4);
  int*   cnt    = (int*)carve((size_t)n * 4);
  int*   off    = (int*)carve((size_t)n * 4);
  int*   flag   = (int*)carve(16);
  int*   bstart = (int*)carve((size_t)(NBUCK + 1) * 4);
  int*   btot   = (int*)carve((size_t)NBUCK * 4);
  int*   M      = (int*)carve((size_t)NCHUNK * NBUCK * 4);
  unsigned short* wfrag = (unsigned short*)carve(65536 * 2);  // 2 x (hi+lo)
  unsigned int* staging = (unsigned int*)carve((size_t)E * 4);
  unsigned short* srcs  = (unsigned short*)carve((size_t)E * 2);
  unsigned short* bufG  = (unsigned short*)carve((size_t)n * DF * 2);
  unsigned short* bufH  = (unsigned short*)carve((size_t)n * DF * 2);

  // CSR build: exact counting sort by bucket = target>>8 (no global atomics)
  prep_kernel<<<3, 256, 0, stream>>>(W1, W2, wfrag, (const unsigned int*)ei, E, flag);
  p1a_kernel<<<NCHUNK, 256, 0, stream>>>(ei, E, flag, M, NBUCK, NCHUNK);
  matscanA_kernel<<<NBUCK, 256, 0, stream>>>(M, btot, NCHUNK);
  matscanB_kernel<<<1, 256, 0, stream>>>(btot, bstart, NBUCK, E);
  p1c_kernel<<<NCHUNK, 256, 0, stream>>>(ei, E, flag, M, bstart, NBUCK, NCHUNK,
                                         staging);
  p2_kernel<<<NBUCK, 256, 0, stream>>>(staging, bstart, off, cnt, dis, srcs, n);

  int gGemm = (n + 31) / 32;        // 1563
  int gAgg  = (n + 7) / 8;          // 6250 (8 waves/block)

  // layer 1: g1 = dis * bf16(x @ W1) ; h1 = bf16(dis*(sum g1 + g1_self) + b1)
  gemm_f32_kernel<<<gGemm, 256, 0, stream>>>(x, wfrag, dis, bufG, n);
  agg_kernel<0><<<gAgg, 512, 0, stream>>>(bufG, srcs, off, cnt, dis, b1, bufH, n);

  // layer 2: g2 = dis * bf16(h1 @ W2) ; out = lrelu(dis*(sum g2 + g2_self) + b2)
  gemm_bf16_kernel<<<gGemm, 256, 0, stream>>>(bufH, wfrag + 32768, dis, bufG, n);
  agg_kernel<1><<<gAgg, 512, 0, stream>>>(bufG, srcs, off, cnt, dis, b2, out, n);
}